// Round 4
// baseline (298.069 us; speedup 1.0000x reference)
//
#include <hip/hip_runtime.h>
#include <stdint.h>

// OKRRouter, fused split-bf16 MFMA GEMM + router.
// K1 prep_b: gate_W^T | secret -> bf16 hi/lo MFMA-fragment-linear layout in ws (1 MB, L2-resident).
// K2 fused: per block 64 tokens; 8 waves = 4 K-quarters x 2 stripes (32 rows/wave).
//   B staged to LDS via global_load_lds(16B); A fp32 loaded + truncation-split in-register;
//   3-term MFMA (Ah*Bh + Ah*Bl + Al*Bh); LDS tree reduction over K-quarters;
//   in-register router epilogue (mask / top-2 / softmax) with margin-guarded exact fp32
//   recompute of near-boundary experts.

#define DDIM 2048
#define NEXP 64
#define NEG_INF  -1000000000.0f
#define MRG_RAW  0.04f
#define MRG_WM   0.15f

typedef __attribute__((ext_vector_type(8))) short bf16x8;
typedef __attribute__((ext_vector_type(4))) float f32x4;

union BFrag { bf16x8 v; uint32_t w[4]; uint4 q; };

// ---- RNE hi/lo split (prep_b only; runs once, accuracy matters most for B) ----
__device__ inline void split8_rne(const float* a, bf16x8* hi, bf16x8* lo) {
    BFrag h, l;
    #pragma unroll
    for (int p = 0; p < 4; ++p) {
        const uint32_t u0 = __float_as_uint(a[2*p]);
        const uint32_t u1 = __float_as_uint(a[2*p+1]);
        const uint32_t h0 = (u0 + 0x7FFFu + ((u0 >> 16) & 1u)) >> 16;
        const uint32_t h1 = (u1 + 0x7FFFu + ((u1 >> 16) & 1u)) >> 16;
        const float r0 = a[2*p]   - __uint_as_float(h0 << 16);   // exact
        const float r1 = a[2*p+1] - __uint_as_float(h1 << 16);
        const uint32_t v0 = __float_as_uint(r0);
        const uint32_t v1 = __float_as_uint(r1);
        const uint32_t l0 = (v0 + 0x7FFFu + ((v0 >> 16) & 1u)) >> 16;
        const uint32_t l1 = (v1 + 0x7FFFu + ((v1 >> 16) & 1u)) >> 16;
        h.w[p] = h0 | (h1 << 16);
        l.w[p] = l0 | (l1 << 16);
    }
    *hi = h.v; *lo = l.v;
}

// ---- cheap truncation split for the A stream (40 VALU vs 112) ----
__device__ inline void split8t(const float* a, bf16x8* hi, bf16x8* lo) {
    BFrag h, l;
    #pragma unroll
    for (int p = 0; p < 4; ++p) {
        const uint32_t u0 = __float_as_uint(a[2*p]);
        const uint32_t u1 = __float_as_uint(a[2*p+1]);
        h.w[p] = (u0 >> 16) | (u1 & 0xFFFF0000u);
        const float r0 = a[2*p]   - __uint_as_float(u0 & 0xFFFF0000u);  // exact residual
        const float r1 = a[2*p+1] - __uint_as_float(u1 & 0xFFFF0000u);
        l.w[p] = (__float_as_uint(r0) >> 16) | (__float_as_uint(r1) & 0xFFFF0000u);
    }
    *hi = h.v; *lo = l.v;
}

// ---- K1: B' fragments. frag f = kstep*8+s is 128 uint4: 64 lanes hi, 64 lanes lo.
// lane l holds B[kstep*32 + (l>>4)*8 + j][s*16 + (l&15)], j=0..7
__global__ void prep_b(const float* __restrict__ gateW, const float* __restrict__ secret,
                       uint4* __restrict__ wsB) {
    const int kstep = blockIdx.x;            // 0..63
    const int s = threadIdx.x >> 6;          // 0..7
    const int l = threadIdx.x & 63;
    const int col = s * 16 + (l & 15);
    const int kb  = kstep * 32 + (l >> 4) * 8;
    float v[8];
    if (col < NEXP) {
        #pragma unroll
        for (int j = 0; j < 8; ++j) v[j] = gateW[(size_t)col * DDIM + kb + j];
    } else {
        #pragma unroll
        for (int j = 0; j < 8; ++j) v[j] = secret[(size_t)(kb + j) * NEXP + (col - NEXP)];
    }
    bf16x8 hi, lo; split8_rne(v, &hi, &lo);
    const size_t base = (size_t)(kstep * 8 + s) * 128 + l;
    BFrag t;
    t.v = hi; wsB[base]      = t.q;
    t.v = lo; wsB[base + 64] = t.q;
}

// ---- async global->LDS, 16B per lane ----
__device__ inline void gl_lds16(const char* g, char* l) {
    __builtin_amdgcn_global_load_lds(
        (const __attribute__((address_space(1))) void*)g,
        (__attribute__((address_space(3))) void*)l, 16, 0, 0);
}

// ---- exact fp32 dots for margin-flagged experts ----
__device__ float dot_raw(const float* __restrict__ x, const float* __restrict__ gw,
                         int row, int e) {
    const float4* a = reinterpret_cast<const float4*>(x + (size_t)row * DDIM);
    const float4* b = reinterpret_cast<const float4*>(gw + (size_t)e * DDIM);
    float s0 = 0.f, s1 = 0.f, s2 = 0.f, s3 = 0.f;
    for (int k = 0; k < DDIM / 4; ++k) {
        const float4 av = a[k], bv = b[k];
        s0 = fmaf(av.x, bv.x, s0);
        s1 = fmaf(av.y, bv.y, s1);
        s2 = fmaf(av.z, bv.z, s2);
        s3 = fmaf(av.w, bv.w, s3);
    }
    return (s0 + s1) + (s2 + s3);
}

__device__ float dot_wm(const float* __restrict__ x, const float* __restrict__ sec,
                        int row, int e) {
    const float* xr = x + (size_t)row * DDIM;
    float s0 = 0.f, s1 = 0.f, s2 = 0.f, s3 = 0.f;
    for (int k = 0; k < DDIM; k += 4) {
        s0 = fmaf(xr[k + 0], sec[(size_t)(k + 0) * NEXP + e], s0);
        s1 = fmaf(xr[k + 1], sec[(size_t)(k + 1) * NEXP + e], s1);
        s2 = fmaf(xr[k + 2], sec[(size_t)(k + 2) * NEXP + e], s2);
        s3 = fmaf(xr[k + 3], sec[(size_t)(k + 3) * NEXP + e], s3);
    }
    return (s0 + s1) + (s2 + s3);
}

// ---- 16-lane-group reductions (xor masks 1,2,4,8 stay within group) ----
__device__ inline float gmax16(float v) {
    #pragma unroll
    for (int off = 1; off <= 8; off <<= 1) v = fmaxf(v, __shfl_xor(v, off));
    return v;
}
__device__ inline float gmin16(float v) {
    #pragma unroll
    for (int off = 1; off <= 8; off <<= 1) v = fminf(v, __shfl_xor(v, off));
    return v;
}

// top-3 insertion / merge with jax.lax.top_k tie semantics (lower index wins on ties)
__device__ inline void ins3(float m, int e, float& v1, int& e1, float& v2, int& e2,
                            float& v3, int& e3) {
    if (m > v1)      { v3 = v2; e3 = e2; v2 = v1; e2 = e1; v1 = m; e1 = e; }
    else if (m > v2) { v3 = v2; e3 = e2; v2 = m;  e2 = e; }
    else if (m > v3) { v3 = m;  e3 = e; }
}
__device__ inline bool better(float av, int ae, float bv, int be) {
    return av > bv || (av == bv && ae < be);
}
__device__ inline void mrg3(float ov, int oe, float& v1, int& e1, float& v2, int& e2,
                            float& v3, int& e3) {
    if (better(ov, oe, v1, e1))      { v3 = v2; e3 = e2; v2 = v1; e2 = e1; v1 = ov; e1 = oe; }
    else if (better(ov, oe, v2, e2)) { v3 = v2; e3 = e2; v2 = ov; e2 = oe; }
    else if (better(ov, oe, v3, e3)) { v3 = ov; e3 = oe; }
}

// ---- K2: fused GEMM + router ----
__global__ __launch_bounds__(512, 2)
void fused_router(const float* __restrict__ x, const uint4* __restrict__ wsB,
                  const float* __restrict__ gateW, const float* __restrict__ secret,
                  float* __restrict__ out, int ntok)
{
    __shared__ __align__(16) char lds[65536];   // staging: 4 quarters x 16 KB; reused for reduction

    const int tid = threadIdx.x;
    const int w = tid >> 6, l = tid & 63;
    const int q = w & 3;           // K-quarter
    const int p = w >> 2;          // stripe (0,1) -> 32 rows each
    const int c = l & 15;          // fragment col / row-in-16
    const int g = l >> 4;          // k-group / C-row group
    const int rowbase = blockIdx.x * 64 + p * 32;

    f32x4 acc[2][8];
    #pragma unroll
    for (int m = 0; m < 2; ++m)
        #pragma unroll
        for (int s = 0; s < 8; ++s) acc[m][s] = (f32x4){0.f, 0.f, 0.f, 0.f};

    const float* xr0 = x + (size_t)(rowbase + c) * DDIM + q * 512 + g * 8;
    const float* xr1 = xr0 + (size_t)16 * DDIM;

    float4 Ac[4], An[4];
    Ac[0] = *reinterpret_cast<const float4*>(xr0);
    Ac[1] = *reinterpret_cast<const float4*>(xr0 + 4);
    Ac[2] = *reinterpret_cast<const float4*>(xr1);
    Ac[3] = *reinterpret_cast<const float4*>(xr1 + 4);
    #pragma unroll
    for (int i = 0; i < 4; ++i) An[i] = Ac[i];

    for (int ts = 0; ts < 16; ++ts) {
        __syncthreads();                       // buf free (prev step's readers done)
        // stage this step's 4 ksteps (one per quarter), 64 KB total, linear lane order
        #pragma unroll
        for (int j = 0; j < 8; ++j) {
            const int qq = j >> 1, sub = j & 1;
            const size_t off = (size_t)sub * 8192 + (size_t)tid * 16;
            gl_lds16(reinterpret_cast<const char*>(wsB) +
                         (size_t)(qq * 16 + ts) * 16384 + off,
                     lds + qq * 16384 + off);
        }
        __syncthreads();                       // drains vmcnt: staged B + Ac visible

        if (ts < 15) {                         // prefetch next A across the barrier
            An[0] = *reinterpret_cast<const float4*>(xr0 + (ts + 1) * 32);
            An[1] = *reinterpret_cast<const float4*>(xr0 + (ts + 1) * 32 + 4);
            An[2] = *reinterpret_cast<const float4*>(xr1 + (ts + 1) * 32);
            An[3] = *reinterpret_cast<const float4*>(xr1 + (ts + 1) * 32 + 4);
        }

        const float va0[8] = {Ac[0].x, Ac[0].y, Ac[0].z, Ac[0].w,
                              Ac[1].x, Ac[1].y, Ac[1].z, Ac[1].w};
        const float va1[8] = {Ac[2].x, Ac[2].y, Ac[2].z, Ac[2].w,
                              Ac[3].x, Ac[3].y, Ac[3].z, Ac[3].w};
        bf16x8 ah0, al0, ah1, al1;
        split8t(va0, &ah0, &al0);
        split8t(va1, &ah1, &al1);

        const char* bb = lds + q * 16384;
        #pragma unroll
        for (int s = 0; s < 8; ++s) {
            const bf16x8 bh = *reinterpret_cast<const bf16x8*>(bb + (s * 2 + 0) * 1024 + l * 16);
            const bf16x8 bl = *reinterpret_cast<const bf16x8*>(bb + (s * 2 + 1) * 1024 + l * 16);
            acc[0][s] = __builtin_amdgcn_mfma_f32_16x16x32_bf16(ah0, bh, acc[0][s], 0, 0, 0);
            acc[0][s] = __builtin_amdgcn_mfma_f32_16x16x32_bf16(ah0, bl, acc[0][s], 0, 0, 0);
            acc[0][s] = __builtin_amdgcn_mfma_f32_16x16x32_bf16(al0, bh, acc[0][s], 0, 0, 0);
            acc[1][s] = __builtin_amdgcn_mfma_f32_16x16x32_bf16(ah1, bh, acc[1][s], 0, 0, 0);
            acc[1][s] = __builtin_amdgcn_mfma_f32_16x16x32_bf16(ah1, bl, acc[1][s], 0, 0, 0);
            acc[1][s] = __builtin_amdgcn_mfma_f32_16x16x32_bf16(al1, bh, acc[1][s], 0, 0, 0);
        }
        #pragma unroll
        for (int i = 0; i < 4; ++i) Ac[i] = An[i];
    }

    // ---- in-block split-K reduction (2 rounds, deterministic) ----
    float* red = reinterpret_cast<float*>(lds);
    __syncthreads();
    if (q == 1 || q == 2) {
        float* L = red + (q == 1 ? 0 : 8192) + p * 4096;
        #pragma unroll
        for (int m = 0; m < 2; ++m)
            #pragma unroll
            for (int s = 0; s < 8; ++s)
                #pragma unroll
                for (int r = 0; r < 4; ++r)
                    L[(m * 16 + g * 4 + r) * 128 + s * 16 + c] = acc[m][s][r];
    }
    __syncthreads();
    if (q == 0) {
        #pragma unroll
        for (int m = 0; m < 2; ++m)
            #pragma unroll
            for (int s = 0; s < 8; ++s)
                #pragma unroll
                for (int r = 0; r < 4; ++r) {
                    const int idx = (m * 16 + g * 4 + r) * 128 + s * 16 + c;
                    acc[m][s][r] += red[p * 4096 + idx] + red[8192 + p * 4096 + idx];
                }
    }
    __syncthreads();
    if (q == 3) {
        float* L = red + p * 4096;
        #pragma unroll
        for (int m = 0; m < 2; ++m)
            #pragma unroll
            for (int s = 0; s < 8; ++s)
                #pragma unroll
                for (int r = 0; r < 4; ++r)
                    L[(m * 16 + g * 4 + r) * 128 + s * 16 + c] = acc[m][s][r];
    }
    __syncthreads();
    if (q != 0) return;

    #pragma unroll
    for (int m = 0; m < 2; ++m)
        #pragma unroll
        for (int s = 0; s < 8; ++s)
            #pragma unroll
            for (int r = 0; r < 4; ++r)
                acc[m][s][r] += red[p * 4096 + (m * 16 + g * 4 + r) * 128 + s * 16 + c];

    // ---- router epilogue: group (16 lanes) owns one row per (m,r) iteration ----
    #pragma unroll
    for (int m = 0; m < 2; ++m) {
        #pragma unroll
        for (int r = 0; r < 4; ++r) {
            const int row = rowbase + m * 16 + g * 4 + r;
            float a0 = acc[m][0][r], a1 = acc[m][1][r], a2 = acc[m][2][r], a3 = acc[m][3][r];
            const float w0 = acc[m][4][r], w1 = acc[m][5][r];
            const float w2 = acc[m][6][r], w3 = acc[m][7][r];

            float rmax = gmax16(fmaxf(fmaxf(a0, a1), fmaxf(a2, a3)));
            float thr  = rmax - 1.5f;

            // guard 1: safe-mask boundary margin -> exact recompute of boundary + top experts
            float dm = fminf(fminf(fabsf(a0 - thr), fabsf(a1 - thr)),
                             fminf(fabsf(a2 - thr), fabsf(a3 - thr)));
            dm = gmin16(dm);
            if (__any(dm < MRG_RAW)) {
                if (dm < MRG_RAW) {                          // group-uniform
                    if (fabsf(a0 - thr) < MRG_RAW || rmax - a0 < MRG_RAW)
                        a0 = dot_raw(x, gateW, row, c);
                    if (fabsf(a1 - thr) < MRG_RAW || rmax - a1 < MRG_RAW)
                        a1 = dot_raw(x, gateW, row, 16 + c);
                    if (fabsf(a2 - thr) < MRG_RAW || rmax - a2 < MRG_RAW)
                        a2 = dot_raw(x, gateW, row, 32 + c);
                    if (fabsf(a3 - thr) < MRG_RAW || rmax - a3 < MRG_RAW)
                        a3 = dot_raw(x, gateW, row, 48 + c);
                }
                rmax = gmax16(fmaxf(fmaxf(a0, a1), fmaxf(a2, a3)));
                thr  = rmax - 1.5f;
            }

            float m0 = (a0 >= thr) ? w0 : NEG_INF;
            float m1 = (a1 >= thr) ? w1 : NEG_INF;
            float m2 = (a2 >= thr) ? w2 : NEG_INF;
            float m3 = (a3 >= thr) ? w3 : NEG_INF;

            float v1 = -3.0e38f, v2 = -3.0e38f, v3 = -3.0e38f;
            int   e1 = 99, e2 = 99, e3 = 99;
            ins3(m0, c,      v1, e1, v2, e2, v3, e3);
            ins3(m1, 16 + c, v1, e1, v2, e2, v3, e3);
            ins3(m2, 32 + c, v1, e1, v2, e2, v3, e3);
            ins3(m3, 48 + c, v1, e1, v2, e2, v3, e3);
            #pragma unroll
            for (int off = 1; off <= 8; off <<= 1) {
                const float ov1 = __shfl_xor(v1, off), ov2 = __shfl_xor(v2, off),
                            ov3 = __shfl_xor(v3, off);
                const int oe1 = __shfl_xor(e1, off), oe2 = __shfl_xor(e2, off),
                          oe3 = __shfl_xor(e3, off);
                mrg3(ov1, oe1, v1, e1, v2, e2, v3, e3);
                mrg3(ov2, oe2, v1, e1, v2, e2, v3, e3);
                mrg3(ov3, oe3, v1, e1, v2, e2, v3, e3);
            }

            // guard 2: close wm ordering among safe candidates -> exact wm recompute
            const bool wf = (v2 > NEG_INF + 1.f) &&
                            ((v1 - v2 < MRG_WM) ||
                             (v3 > NEG_INF + 1.f && v2 - v3 < MRG_WM));
            if (__any(wf)) {
                if (wf) {                                    // group-uniform
                    if (m0 > NEG_INF + 1.f && m0 >= v2 - MRG_WM) m0 = dot_wm(x, secret, row, c);
                    if (m1 > NEG_INF + 1.f && m1 >= v2 - MRG_WM) m1 = dot_wm(x, secret, row, 16 + c);
                    if (m2 > NEG_INF + 1.f && m2 >= v2 - MRG_WM) m2 = dot_wm(x, secret, row, 32 + c);
                    if (m3 > NEG_INF + 1.f && m3 >= v2 - MRG_WM) m3 = dot_wm(x, secret, row, 48 + c);
                }
                v1 = v2 = v3 = -3.0e38f; e1 = e2 = e3 = 99;
                ins3(m0, c,      v1, e1, v2, e2, v3, e3);
                ins3(m1, 16 + c, v1, e1, v2, e2, v3, e3);
                ins3(m2, 32 + c, v1, e1, v2, e2, v3, e3);
                ins3(m3, 48 + c, v1, e1, v2, e2, v3, e3);
                #pragma unroll
                for (int off = 1; off <= 8; off <<= 1) {
                    const float ov1 = __shfl_xor(v1, off), ov2 = __shfl_xor(v2, off),
                                ov3 = __shfl_xor(v3, off);
                    const int oe1 = __shfl_xor(e1, off), oe2 = __shfl_xor(e2, off),
                              oe3 = __shfl_xor(e3, off);
                    mrg3(ov1, oe1, v1, e1, v2, e2, v3, e3);
                    mrg3(ov2, oe2, v1, e1, v2, e2, v3, e3);
                    mrg3(ov3, oe3, v1, e1, v2, e2, v3, e3);
                }
            }

            // gather raw logits at e1, e2 (group-uniform indices)
            const int s1 = e1 >> 4, c1 = e1 & 15;
            const float ra = (s1 == 0) ? a0 : (s1 == 1) ? a1 : (s1 == 2) ? a2 : a3;
            const float l1v = __shfl(ra, (l & 0x30) | c1);
            const int s2 = e2 >> 4, c2 = e2 & 15;
            const float rb = (s2 == 0) ? a0 : (s2 == 1) ? a1 : (s2 == 2) ? a2 : a3;
            const float l2v = __shfl(rb, (l & 0x30) | c2);

            if (c == 0) {
                const float mm = fmaxf(l1v, l2v);
                const float x1 = expf(l1v - mm), x2 = expf(l2v - mm);
                const float inv = 1.0f / (x1 + x2);
                out[(size_t)row * 2 + 0] = x1 * inv;
                out[(size_t)row * 2 + 1] = x2 * inv;
                out[(size_t)2 * ntok + row * 2 + 0] = (float)e1;
                out[(size_t)2 * ntok + row * 2 + 1] = (float)e2;
            }
        }
    }
}

extern "C" void kernel_launch(void* const* d_in, const int* in_sizes, int n_in,
                              void* d_out, int out_size, void* d_ws, size_t ws_size,
                              hipStream_t stream) {
    const float* x      = (const float*)d_in[0];
    const float* gateW  = (const float*)d_in[1];
    const float* secret = (const float*)d_in[2];
    float* out = (float*)d_out;

    const int ntok = in_sizes[0] / DDIM;       // 16384
    uint4* wsB = (uint4*)d_ws;                 // 1 MB of bf16 hi/lo fragments

    prep_b<<<64, 512, 0, stream>>>(gateW, secret, wsB);
    fused_router<<<ntok / 64, 512, 0, stream>>>(x, wsB, gateW, secret, out, ntok);
}

// Round 5
// 164.469 us; speedup vs baseline: 1.8123x; 1.8123x over previous
//
#include <hip/hip_runtime.h>
#include <stdint.h>

// OKRRouter, fused split-bf16 MFMA GEMM + in-block split-K + router.
// K1 prep_b: gate_W^T | secret -> bf16 hi/lo fragment-linear layout in ws (1 MB, L2/L3-resident).
// K2 fused:  32 tokens/block, 256 thr; wave q owns K-quarter q (barrier-free main loop,
//   B straight from L2 like round 3). LDS only for split-K reduction (stride-132 pad).
//   Epilogue reads reduced logits from LDS, spread over all 4 waves; margin-guarded exact
//   fp32 recompute (validated round 3/4).

#define DDIM 2048
#define NEXP 64
#define NEG_INF  -1000000000.0f
#define MRG_RAW  0.04f
#define MRG_WM   0.15f
#define RST      132      // LDS reduction row stride (floats): 2-way banks only

typedef __attribute__((ext_vector_type(8))) short bf16x8;
typedef __attribute__((ext_vector_type(4))) float f32x4;

union BFrag { bf16x8 v; uint32_t w[4]; uint4 q; };

// ---- RNE hi/lo split (prep_b only) ----
__device__ inline void split8_rne(const float* a, bf16x8* hi, bf16x8* lo) {
    BFrag h, l;
    #pragma unroll
    for (int p = 0; p < 4; ++p) {
        const uint32_t u0 = __float_as_uint(a[2*p]);
        const uint32_t u1 = __float_as_uint(a[2*p+1]);
        const uint32_t h0 = (u0 + 0x7FFFu + ((u0 >> 16) & 1u)) >> 16;
        const uint32_t h1 = (u1 + 0x7FFFu + ((u1 >> 16) & 1u)) >> 16;
        const float r0 = a[2*p]   - __uint_as_float(h0 << 16);
        const float r1 = a[2*p+1] - __uint_as_float(h1 << 16);
        const uint32_t v0 = __float_as_uint(r0);
        const uint32_t v1 = __float_as_uint(r1);
        const uint32_t l0 = (v0 + 0x7FFFu + ((v0 >> 16) & 1u)) >> 16;
        const uint32_t l1 = (v1 + 0x7FFFu + ((v1 >> 16) & 1u)) >> 16;
        h.w[p] = h0 | (h1 << 16);
        l.w[p] = l0 | (l1 << 16);
    }
    *hi = h.v; *lo = l.v;
}

// ---- cheap truncation split for the A stream (validated round 4) ----
__device__ inline void split8t(const float* a, bf16x8* hi, bf16x8* lo) {
    BFrag h, l;
    #pragma unroll
    for (int p = 0; p < 4; ++p) {
        const uint32_t u0 = __float_as_uint(a[2*p]);
        const uint32_t u1 = __float_as_uint(a[2*p+1]);
        h.w[p] = (u0 >> 16) | (u1 & 0xFFFF0000u);
        const float r0 = a[2*p]   - __uint_as_float(u0 & 0xFFFF0000u);
        const float r1 = a[2*p+1] - __uint_as_float(u1 & 0xFFFF0000u);
        l.w[p] = (__float_as_uint(r0) >> 16) | (__float_as_uint(r1) & 0xFFFF0000u);
    }
    *hi = h.v; *lo = l.v;
}

// ---- K1: B' fragments. frag f = kstep*8+s is 128 uint4: 64 lanes hi, 64 lanes lo.
// lane l holds B[kstep*32 + (l>>4)*8 + j][s*16 + (l&15)], j=0..7
__global__ void prep_b(const float* __restrict__ gateW, const float* __restrict__ secret,
                       uint4* __restrict__ wsB) {
    const int kstep = blockIdx.x;            // 0..63
    const int s = threadIdx.x >> 6;          // 0..7
    const int l = threadIdx.x & 63;
    const int col = s * 16 + (l & 15);
    const int kb  = kstep * 32 + (l >> 4) * 8;
    float v[8];
    if (col < NEXP) {
        #pragma unroll
        for (int j = 0; j < 8; ++j) v[j] = gateW[(size_t)col * DDIM + kb + j];
    } else {
        #pragma unroll
        for (int j = 0; j < 8; ++j) v[j] = secret[(size_t)(kb + j) * NEXP + (col - NEXP)];
    }
    bf16x8 hi, lo; split8_rne(v, &hi, &lo);
    const size_t base = (size_t)(kstep * 8 + s) * 128 + l;
    BFrag t;
    t.v = hi; wsB[base]      = t.q;
    t.v = lo; wsB[base + 64] = t.q;
}

// ---- exact fp32 dots for margin-flagged experts ----
__device__ float dot_raw(const float* __restrict__ x, const float* __restrict__ gw,
                         int row, int e) {
    const float4* a = reinterpret_cast<const float4*>(x + (size_t)row * DDIM);
    const float4* b = reinterpret_cast<const float4*>(gw + (size_t)e * DDIM);
    float s0 = 0.f, s1 = 0.f, s2 = 0.f, s3 = 0.f;
    for (int k = 0; k < DDIM / 4; ++k) {
        const float4 av = a[k], bv = b[k];
        s0 = fmaf(av.x, bv.x, s0);
        s1 = fmaf(av.y, bv.y, s1);
        s2 = fmaf(av.z, bv.z, s2);
        s3 = fmaf(av.w, bv.w, s3);
    }
    return (s0 + s1) + (s2 + s3);
}

__device__ float dot_wm(const float* __restrict__ x, const float* __restrict__ sec,
                        int row, int e) {
    const float* xr = x + (size_t)row * DDIM;
    float s0 = 0.f, s1 = 0.f, s2 = 0.f, s3 = 0.f;
    for (int k = 0; k < DDIM; k += 4) {
        s0 = fmaf(xr[k + 0], sec[(size_t)(k + 0) * NEXP + e], s0);
        s1 = fmaf(xr[k + 1], sec[(size_t)(k + 1) * NEXP + e], s1);
        s2 = fmaf(xr[k + 2], sec[(size_t)(k + 2) * NEXP + e], s2);
        s3 = fmaf(xr[k + 3], sec[(size_t)(k + 3) * NEXP + e], s3);
    }
    return (s0 + s1) + (s2 + s3);
}

// ---- 16-lane-group reductions ----
__device__ inline float gmax16(float v) {
    #pragma unroll
    for (int off = 1; off <= 8; off <<= 1) v = fmaxf(v, __shfl_xor(v, off));
    return v;
}
__device__ inline float gmin16(float v) {
    #pragma unroll
    for (int off = 1; off <= 8; off <<= 1) v = fminf(v, __shfl_xor(v, off));
    return v;
}

// top-3 insertion / merge, jax.lax.top_k tie semantics (lower index wins)
__device__ inline void ins3(float m, int e, float& v1, int& e1, float& v2, int& e2,
                            float& v3, int& e3) {
    if (m > v1)      { v3 = v2; e3 = e2; v2 = v1; e2 = e1; v1 = m; e1 = e; }
    else if (m > v2) { v3 = v2; e3 = e2; v2 = m;  e2 = e; }
    else if (m > v3) { v3 = m;  e3 = e; }
}
__device__ inline bool better(float av, int ae, float bv, int be) {
    return av > bv || (av == bv && ae < be);
}
__device__ inline void mrg3(float ov, int oe, float& v1, int& e1, float& v2, int& e2,
                            float& v3, int& e3) {
    if (better(ov, oe, v1, e1))      { v3 = v2; e3 = e2; v2 = v1; e2 = e1; v1 = ov; e1 = oe; }
    else if (better(ov, oe, v2, e2)) { v3 = v2; e3 = e2; v2 = ov; e2 = oe; }
    else if (better(ov, oe, v3, e3)) { v3 = ov; e3 = oe; }
}

// ---- K2: fused GEMM (in-block split-K) + router ----
__global__ __launch_bounds__(256, 2)
void fused_gemm_router(const float* __restrict__ x, const uint4* __restrict__ wsB,
                       const float* __restrict__ gateW, const float* __restrict__ secret,
                       float* __restrict__ out, int ntok)
{
    __shared__ float red[3][32 * RST];   // 50.7 KB, reduction only

    const int tid = threadIdx.x;
    const int q = tid >> 6;        // wave = K-quarter
    const int l = tid & 63;
    const int c = l & 15;          // row-in-16 / col-in-16
    const int g = l >> 4;          // k-group / C-row group
    const int rowbase = blockIdx.x * 32;

    f32x4 acc[2][8];
    #pragma unroll
    for (int m = 0; m < 2; ++m)
        #pragma unroll
        for (int s = 0; s < 8; ++s) acc[m][s] = (f32x4){0.f, 0.f, 0.f, 0.f};

    const float* xr0 = x + (size_t)(rowbase + c) * DDIM + q * 512 + g * 8;
    const float* xr1 = xr0 + (size_t)16 * DDIM;
    const uint4* bp  = wsB + (size_t)(q * 16 * 8) * 128 + l;

    // barrier-free main loop: compiler pipelines A (HBM) and B (L2) loads freely
    for (int ts = 0; ts < 16; ++ts) {
        const float4 a0 = *reinterpret_cast<const float4*>(xr0 + ts * 32);
        const float4 a1 = *reinterpret_cast<const float4*>(xr0 + ts * 32 + 4);
        const float4 a2 = *reinterpret_cast<const float4*>(xr1 + ts * 32);
        const float4 a3 = *reinterpret_cast<const float4*>(xr1 + ts * 32 + 4);
        const float va0[8] = {a0.x, a0.y, a0.z, a0.w, a1.x, a1.y, a1.z, a1.w};
        const float va1[8] = {a2.x, a2.y, a2.z, a2.w, a3.x, a3.y, a3.z, a3.w};
        bf16x8 ah0, al0, ah1, al1;
        split8t(va0, &ah0, &al0);
        split8t(va1, &ah1, &al1);

        #pragma unroll
        for (int s = 0; s < 8; ++s) {
            BFrag th, tl;
            th.q = bp[(size_t)(ts * 8 + s) * 128];
            tl.q = bp[(size_t)(ts * 8 + s) * 128 + 64];
            const bf16x8 bh = th.v, bl = tl.v;
            acc[0][s] = __builtin_amdgcn_mfma_f32_16x16x32_bf16(ah0, bh, acc[0][s], 0, 0, 0);
            acc[0][s] = __builtin_amdgcn_mfma_f32_16x16x32_bf16(ah0, bl, acc[0][s], 0, 0, 0);
            acc[0][s] = __builtin_amdgcn_mfma_f32_16x16x32_bf16(al0, bh, acc[0][s], 0, 0, 0);
            acc[1][s] = __builtin_amdgcn_mfma_f32_16x16x32_bf16(ah1, bh, acc[1][s], 0, 0, 0);
            acc[1][s] = __builtin_amdgcn_mfma_f32_16x16x32_bf16(ah1, bl, acc[1][s], 0, 0, 0);
            acc[1][s] = __builtin_amdgcn_mfma_f32_16x16x32_bf16(al1, bh, acc[1][s], 0, 0, 0);
        }
    }

    // ---- split-K reduction in LDS (C/D layout: row=(l>>4)*4+reg, col=l&15) ----
    if (q != 0) {
        float* L = red[q - 1];
        #pragma unroll
        for (int m = 0; m < 2; ++m)
            #pragma unroll
            for (int s = 0; s < 8; ++s)
                #pragma unroll
                for (int r = 0; r < 4; ++r)
                    L[(m * 16 + g * 4 + r) * RST + s * 16 + c] = acc[m][s][r];
    }
    __syncthreads();
    if (q == 0) {
        #pragma unroll
        for (int m = 0; m < 2; ++m)
            #pragma unroll
            for (int s = 0; s < 8; ++s)
                #pragma unroll
                for (int r = 0; r < 4; ++r) {
                    const int idx = (m * 16 + g * 4 + r) * RST + s * 16 + c;
                    const float v = acc[m][s][r] + red[0][idx] + red[1][idx] + red[2][idx];
                    red[0][idx] = v;     // read-then-write, wave-local ordering safe
                }
    }
    __syncthreads();

    // ---- epilogue: each wave handles 2 of the 8 (m,r) row-groups ----
    const float* red0 = red[0];
    for (int p2 = q * 2; p2 < q * 2 + 2; ++p2) {
        const int mi = p2 >> 2, r = p2 & 3;
        const int row = rowbase + mi * 16 + g * 4 + r;
        const float* R = &red0[(mi * 16 + g * 4 + r) * RST];

        float a0 = R[c], a1 = R[16 + c], a2 = R[32 + c], a3 = R[48 + c];
        const float w0 = R[64 + c], w1 = R[80 + c], w2 = R[96 + c], w3 = R[112 + c];

        float rmax = gmax16(fmaxf(fmaxf(a0, a1), fmaxf(a2, a3)));
        float thr  = rmax - 1.5f;

        // guard 1: near safe-mask boundary -> exact fp32 recompute of boundary + top experts
        float dm = fminf(fminf(fabsf(a0 - thr), fabsf(a1 - thr)),
                         fminf(fabsf(a2 - thr), fabsf(a3 - thr)));
        dm = gmin16(dm);
        if (__any(dm < MRG_RAW)) {
            if (dm < MRG_RAW) {                          // group-uniform
                if (fabsf(a0 - thr) < MRG_RAW || rmax - a0 < MRG_RAW)
                    a0 = dot_raw(x, gateW, row, c);
                if (fabsf(a1 - thr) < MRG_RAW || rmax - a1 < MRG_RAW)
                    a1 = dot_raw(x, gateW, row, 16 + c);
                if (fabsf(a2 - thr) < MRG_RAW || rmax - a2 < MRG_RAW)
                    a2 = dot_raw(x, gateW, row, 32 + c);
                if (fabsf(a3 - thr) < MRG_RAW || rmax - a3 < MRG_RAW)
                    a3 = dot_raw(x, gateW, row, 48 + c);
            }
            rmax = gmax16(fmaxf(fmaxf(a0, a1), fmaxf(a2, a3)));
            thr  = rmax - 1.5f;
        }

        float m0 = (a0 >= thr) ? w0 : NEG_INF;
        float m1 = (a1 >= thr) ? w1 : NEG_INF;
        float m2 = (a2 >= thr) ? w2 : NEG_INF;
        float m3 = (a3 >= thr) ? w3 : NEG_INF;

        float v1 = -3.0e38f, v2 = -3.0e38f, v3 = -3.0e38f;
        int   e1 = 99, e2 = 99, e3 = 99;
        ins3(m0, c,      v1, e1, v2, e2, v3, e3);
        ins3(m1, 16 + c, v1, e1, v2, e2, v3, e3);
        ins3(m2, 32 + c, v1, e1, v2, e2, v3, e3);
        ins3(m3, 48 + c, v1, e1, v2, e2, v3, e3);
        #pragma unroll
        for (int off = 1; off <= 8; off <<= 1) {
            const float ov1 = __shfl_xor(v1, off), ov2 = __shfl_xor(v2, off),
                        ov3 = __shfl_xor(v3, off);
            const int oe1 = __shfl_xor(e1, off), oe2 = __shfl_xor(e2, off),
                      oe3 = __shfl_xor(e3, off);
            mrg3(ov1, oe1, v1, e1, v2, e2, v3, e3);
            mrg3(ov2, oe2, v1, e1, v2, e2, v3, e3);
            mrg3(ov3, oe3, v1, e1, v2, e2, v3, e3);
        }

        // guard 2: close wm ordering among safe candidates -> exact fp32 wm
        const bool wf = (v2 > NEG_INF + 1.f) &&
                        ((v1 - v2 < MRG_WM) ||
                         (v3 > NEG_INF + 1.f && v2 - v3 < MRG_WM));
        if (__any(wf)) {
            if (wf) {                                    // group-uniform
                if (m0 > NEG_INF + 1.f && m0 >= v2 - MRG_WM) m0 = dot_wm(x, secret, row, c);
                if (m1 > NEG_INF + 1.f && m1 >= v2 - MRG_WM) m1 = dot_wm(x, secret, row, 16 + c);
                if (m2 > NEG_INF + 1.f && m2 >= v2 - MRG_WM) m2 = dot_wm(x, secret, row, 32 + c);
                if (m3 > NEG_INF + 1.f && m3 >= v2 - MRG_WM) m3 = dot_wm(x, secret, row, 48 + c);
            }
            v1 = v2 = v3 = -3.0e38f; e1 = e2 = e3 = 99;
            ins3(m0, c,      v1, e1, v2, e2, v3, e3);
            ins3(m1, 16 + c, v1, e1, v2, e2, v3, e3);
            ins3(m2, 32 + c, v1, e1, v2, e2, v3, e3);
            ins3(m3, 48 + c, v1, e1, v2, e2, v3, e3);
            #pragma unroll
            for (int off = 1; off <= 8; off <<= 1) {
                const float ov1 = __shfl_xor(v1, off), ov2 = __shfl_xor(v2, off),
                            ov3 = __shfl_xor(v3, off);
                const int oe1 = __shfl_xor(e1, off), oe2 = __shfl_xor(e2, off),
                          oe3 = __shfl_xor(e3, off);
                mrg3(ov1, oe1, v1, e1, v2, e2, v3, e3);
                mrg3(ov2, oe2, v1, e1, v2, e2, v3, e3);
                mrg3(ov3, oe3, v1, e1, v2, e2, v3, e3);
            }
        }

        // gather raw logits at e1, e2 (group-uniform)
        const int s1 = e1 >> 4, c1 = e1 & 15;
        const float ra = (s1 == 0) ? a0 : (s1 == 1) ? a1 : (s1 == 2) ? a2 : a3;
        const float l1v = __shfl(ra, (l & 0x30) | c1);
        const int s2 = e2 >> 4, c2 = e2 & 15;
        const float rb = (s2 == 0) ? a0 : (s2 == 1) ? a1 : (s2 == 2) ? a2 : a3;
        const float l2v = __shfl(rb, (l & 0x30) | c2);

        if (c == 0) {
            const float mm = fmaxf(l1v, l2v);
            const float x1 = expf(l1v - mm), x2 = expf(l2v - mm);
            const float inv = 1.0f / (x1 + x2);
            out[(size_t)row * 2 + 0] = x1 * inv;
            out[(size_t)row * 2 + 1] = x2 * inv;
            out[(size_t)2 * ntok + row * 2 + 0] = (float)e1;
            out[(size_t)2 * ntok + row * 2 + 1] = (float)e2;
        }
    }
}

extern "C" void kernel_launch(void* const* d_in, const int* in_sizes, int n_in,
                              void* d_out, int out_size, void* d_ws, size_t ws_size,
                              hipStream_t stream) {
    const float* x      = (const float*)d_in[0];
    const float* gateW  = (const float*)d_in[1];
    const float* secret = (const float*)d_in[2];
    float* out = (float*)d_out;

    const int ntok = in_sizes[0] / DDIM;       // 16384
    uint4* wsB = (uint4*)d_ws;                 // 1 MB of bf16 hi/lo fragments

    prep_b<<<64, 512, 0, stream>>>(gateW, secret, wsB);
    fused_gemm_router<<<ntok / 32, 256, 0, stream>>>(x, wsB, gateW, secret, out, ntok);
}

// Round 6
// 117.243 us; speedup vs baseline: 2.5423x; 1.4028x over previous
//
#include <hip/hip_runtime.h>
#include <stdint.h>

// OKRRouter, split-bf16 MFMA, 3 slim kernels (de-fused for codegen health):
// K1 prep_b: gate_W^T | secret -> bf16 hi/lo fragment-linear layout in ws (1 MB, L2-resident).
// K2 gemm32: 32 tokens/block, 4 waves = 2 token-stripes x 2 K-halves; batched B-loads
//            (16 fragments in flight before MFMAs); LDS reduction of the 2 K-halves;
//            writes 128 reduced fp32 logits per token to ws (8.4 MB).
// K3 router: 1 wave per token; mask/top-2/softmax with margin-guarded exact fp32
//            recompute (validated rounds 3-5).

#define DDIM 2048
#define NEXP 64
#define NEG_INF  -1000000000.0f
#define MRG_RAW  0.04f
#define MRG_WM   0.15f
#define RST      130     // LDS reduction row stride (floats)

typedef __attribute__((ext_vector_type(8))) short bf16x8;
typedef __attribute__((ext_vector_type(4))) float f32x4;

union BFrag { bf16x8 v; uint32_t w[4]; uint4 q; };

// ---- RNE hi/lo split (prep_b only) ----
__device__ inline void split8_rne(const float* a, bf16x8* hi, bf16x8* lo) {
    BFrag h, l;
    #pragma unroll
    for (int p = 0; p < 4; ++p) {
        const uint32_t u0 = __float_as_uint(a[2*p]);
        const uint32_t u1 = __float_as_uint(a[2*p+1]);
        const uint32_t h0 = (u0 + 0x7FFFu + ((u0 >> 16) & 1u)) >> 16;
        const uint32_t h1 = (u1 + 0x7FFFu + ((u1 >> 16) & 1u)) >> 16;
        const float r0 = a[2*p]   - __uint_as_float(h0 << 16);
        const float r1 = a[2*p+1] - __uint_as_float(h1 << 16);
        const uint32_t v0 = __float_as_uint(r0);
        const uint32_t v1 = __float_as_uint(r1);
        const uint32_t l0 = (v0 + 0x7FFFu + ((v0 >> 16) & 1u)) >> 16;
        const uint32_t l1 = (v1 + 0x7FFFu + ((v1 >> 16) & 1u)) >> 16;
        h.w[p] = h0 | (h1 << 16);
        l.w[p] = l0 | (l1 << 16);
    }
    *hi = h.v; *lo = l.v;
}

// ---- cheap truncation split for the A stream (validated round 4/5) ----
__device__ inline void split8t(const float* a, bf16x8* hi, bf16x8* lo) {
    BFrag h, l;
    #pragma unroll
    for (int p = 0; p < 4; ++p) {
        const uint32_t u0 = __float_as_uint(a[2*p]);
        const uint32_t u1 = __float_as_uint(a[2*p+1]);
        h.w[p] = (u0 >> 16) | (u1 & 0xFFFF0000u);
        const float r0 = a[2*p]   - __uint_as_float(u0 & 0xFFFF0000u);
        const float r1 = a[2*p+1] - __uint_as_float(u1 & 0xFFFF0000u);
        l.w[p] = (__float_as_uint(r0) >> 16) | (__float_as_uint(r1) & 0xFFFF0000u);
    }
    *hi = h.v; *lo = l.v;
}

// ---- K1: B' fragments. frag f = kstep*8+s is 128 slots of 16B: 64 lanes hi, 64 lanes lo.
// lane l holds B[kstep*32 + (l>>4)*8 + j][s*16 + (l&15)], j=0..7
__global__ void prep_b(const float* __restrict__ gateW, const float* __restrict__ secret,
                       uint4* __restrict__ wsB) {
    const int kstep = blockIdx.x;            // 0..63
    const int s = threadIdx.x >> 6;          // 0..7
    const int l = threadIdx.x & 63;
    const int col = s * 16 + (l & 15);
    const int kb  = kstep * 32 + (l >> 4) * 8;
    float v[8];
    if (col < NEXP) {
        #pragma unroll
        for (int j = 0; j < 8; ++j) v[j] = gateW[(size_t)col * DDIM + kb + j];
    } else {
        #pragma unroll
        for (int j = 0; j < 8; ++j) v[j] = secret[(size_t)(kb + j) * NEXP + (col - NEXP)];
    }
    bf16x8 hi, lo; split8_rne(v, &hi, &lo);
    const size_t base = (size_t)(kstep * 8 + s) * 128 + l;
    BFrag t;
    t.v = hi; wsB[base]      = t.q;
    t.v = lo; wsB[base + 64] = t.q;
}

// ---- K2: GEMM. 32 tokens/block, 256 thr: wave = stripe p (16 tokens) x K-half h (1024) ----
__global__ __launch_bounds__(256, 3)
void gemm32(const float* __restrict__ x, const bf16x8* __restrict__ wsB,
            float* __restrict__ wsL, int ntok)
{
    __shared__ float red[2][16 * RST];   // 16.6 KB: h==1 partials per stripe

    const int tid = threadIdx.x;
    const int w = tid >> 6;
    const int p = w & 1;           // token stripe
    const int h = w >> 1;          // K-half
    const int l = tid & 63;
    const int c = l & 15;
    const int g = l >> 4;
    const int rowbase = blockIdx.x * 32 + p * 16;

    f32x4 acc[8];
    #pragma unroll
    for (int s = 0; s < 8; ++s) acc[s] = (f32x4){0.f, 0.f, 0.f, 0.f};

    const float* xr = x + (size_t)(rowbase + c) * DDIM + h * 1024 + g * 8;
    const bf16x8* bp = wsB + ((size_t)h * 32 * 8) * 128 + l;

    for (int ts = 0; ts < 32; ++ts) {
        // batch all 16 B fragments first: 16 independent 16B loads in flight
        bf16x8 bq[16];
        #pragma unroll
        for (int s = 0; s < 8; ++s) {
            bq[2*s]     = bp[(size_t)(ts * 8 + s) * 128];
            bq[2*s + 1] = bp[(size_t)(ts * 8 + s) * 128 + 64];
        }
        const float4 a0 = *reinterpret_cast<const float4*>(xr + ts * 32);
        const float4 a1 = *reinterpret_cast<const float4*>(xr + ts * 32 + 4);
        const float va[8] = {a0.x, a0.y, a0.z, a0.w, a1.x, a1.y, a1.z, a1.w};
        bf16x8 ah, al;
        split8t(va, &ah, &al);

        #pragma unroll
        for (int s = 0; s < 8; ++s) {
            acc[s] = __builtin_amdgcn_mfma_f32_16x16x32_bf16(ah, bq[2*s],     acc[s], 0, 0, 0);
            acc[s] = __builtin_amdgcn_mfma_f32_16x16x32_bf16(ah, bq[2*s + 1], acc[s], 0, 0, 0);
            acc[s] = __builtin_amdgcn_mfma_f32_16x16x32_bf16(al, bq[2*s],     acc[s], 0, 0, 0);
        }
    }

    // C/D layout: row = (l>>4)*4 + reg, col = l&15
    if (h == 1) {
        float* L = red[p];
        #pragma unroll
        for (int s = 0; s < 8; ++s)
            #pragma unroll
            for (int r = 0; r < 4; ++r)
                L[(g * 4 + r) * RST + s * 16 + c] = acc[s][r];
    }
    __syncthreads();
    if (h == 0) {
        const float* L = red[p];
        #pragma unroll
        for (int s = 0; s < 8; ++s)
            #pragma unroll
            for (int r = 0; r < 4; ++r) {
                const float v = acc[s][r] + L[(g * 4 + r) * RST + s * 16 + c];
                wsL[(size_t)(rowbase + g * 4 + r) * 128 + s * 16 + c] = v;
            }
    }
}

// ---- K3: router, 1 wave per token ----
__global__ __launch_bounds__(256, 4)
void router_k(const float* __restrict__ wsL,
              const float* __restrict__ x,
              const float* __restrict__ gateW,
              const float* __restrict__ secret,
              float* __restrict__ out, int ntok)
{
    const int t = blockIdx.x * 4 + (threadIdx.x >> 6);
    const int e = threadIdx.x & 63;

    float raw = wsL[(size_t)t * 128 + e];
    float wm  = wsL[(size_t)t * 128 + NEXP + e];

    float rmax = raw;
    #pragma unroll
    for (int off = 32; off; off >>= 1) rmax = fmaxf(rmax, __shfl_xor(rmax, off));

    // guard 1: safe-mask boundary margin -> exact fp32 raw recompute (whole token)
    if (__any(fabsf(raw - (rmax - 1.5f)) < MRG_RAW)) {
        float s0 = 0.f, s1 = 0.f, s2 = 0.f, s3 = 0.f;
        const float4* xr = reinterpret_cast<const float4*>(x + (size_t)t * DDIM);
        const float4* wr = reinterpret_cast<const float4*>(gateW + (size_t)e * DDIM);
        for (int k = 0; k < DDIM / 4; ++k) {
            const float4 a = xr[k], b = wr[k];
            s0 = fmaf(a.x, b.x, s0); s1 = fmaf(a.y, b.y, s1);
            s2 = fmaf(a.z, b.z, s2); s3 = fmaf(a.w, b.w, s3);
        }
        raw = (s0 + s1) + (s2 + s3);
        rmax = raw;
        #pragma unroll
        for (int off = 32; off; off >>= 1) rmax = fmaxf(rmax, __shfl_xor(rmax, off));
    }

    const bool safe = (raw >= rmax - 1.5f);
    float m = safe ? wm : NEG_INF;

    // top-3 (value desc, lowest index on ties = jax.lax.top_k)
    float v1 = m; int e1 = e;
    #pragma unroll
    for (int off = 32; off; off >>= 1) {
        const float ov = __shfl_xor(v1, off); const int oi = __shfl_xor(e1, off);
        if (ov > v1 || (ov == v1 && oi < e1)) { v1 = ov; e1 = oi; }
    }
    float v2 = (e == e1) ? -3.0e38f : m; int e2 = e;
    #pragma unroll
    for (int off = 32; off; off >>= 1) {
        const float ov = __shfl_xor(v2, off); const int oi = __shfl_xor(e2, off);
        if (ov > v2 || (ov == v2 && oi < e2)) { v2 = ov; e2 = oi; }
    }
    float v3 = (e == e1 || e == e2) ? -3.0e38f : m; int e3 = e;
    #pragma unroll
    for (int off = 32; off; off >>= 1) {
        const float ov = __shfl_xor(v3, off); const int oi = __shfl_xor(e3, off);
        if (ov > v3 || (ov == v3 && oi < e3)) { v3 = ov; e3 = oi; }
    }

    // guard 2: close wm ordering among safe candidates -> exact fp32 wm recompute
    const bool wmRisk = (v2 > NEG_INF + 1.0f && v1 - v2 < MRG_WM) ||
                        (v3 > NEG_INF + 1.0f && v2 - v3 < MRG_WM);
    if (__any(wmRisk)) {
        float s0 = 0.f, s1 = 0.f, s2 = 0.f, s3 = 0.f;
        const float* xr = x + (size_t)t * DDIM;
        for (int k = 0; k < DDIM; k += 4) {
            s0 = fmaf(xr[k + 0], secret[(size_t)(k + 0) * NEXP + e], s0);
            s1 = fmaf(xr[k + 1], secret[(size_t)(k + 1) * NEXP + e], s1);
            s2 = fmaf(xr[k + 2], secret[(size_t)(k + 2) * NEXP + e], s2);
            s3 = fmaf(xr[k + 3], secret[(size_t)(k + 3) * NEXP + e], s3);
        }
        m = safe ? ((s0 + s1) + (s2 + s3)) : NEG_INF;
        v1 = m; e1 = e;
        #pragma unroll
        for (int off = 32; off; off >>= 1) {
            const float ov = __shfl_xor(v1, off); const int oi = __shfl_xor(e1, off);
            if (ov > v1 || (ov == v1 && oi < e1)) { v1 = ov; e1 = oi; }
        }
        v2 = (e == e1) ? -3.0e38f : m; e2 = e;
        #pragma unroll
        for (int off = 32; off; off >>= 1) {
            const float ov = __shfl_xor(v2, off); const int oi = __shfl_xor(e2, off);
            if (ov > v2 || (ov == v2 && oi < e2)) { v2 = ov; e2 = oi; }
        }
    }

    const float l1 = __shfl(raw, e1);
    const float l2 = __shfl(raw, e2);

    if (e == 0) {
        const float mm = fmaxf(l1, l2);
        const float x1 = expf(l1 - mm), x2 = expf(l2 - mm);
        const float inv = 1.0f / (x1 + x2);
        out[(size_t)t * 2 + 0] = x1 * inv;
        out[(size_t)t * 2 + 1] = x2 * inv;
        out[(size_t)2 * ntok + t * 2 + 0] = (float)e1;
        out[(size_t)2 * ntok + t * 2 + 1] = (float)e2;
    }
}

extern "C" void kernel_launch(void* const* d_in, const int* in_sizes, int n_in,
                              void* d_out, int out_size, void* d_ws, size_t ws_size,
                              hipStream_t stream) {
    const float* x      = (const float*)d_in[0];
    const float* gateW  = (const float*)d_in[1];
    const float* secret = (const float*)d_in[2];
    float* out = (float*)d_out;

    const int ntok = in_sizes[0] / DDIM;                 // 16384
    uint4* wsB = (uint4*)d_ws;                           // 1 MB fragments
    float* wsL = (float*)((char*)d_ws + (2u << 20));     // 8 MB logits [ntok][128]

    prep_b<<<64, 512, 0, stream>>>(gateW, secret, wsB);
    gemm32<<<ntok / 32, 256, 0, stream>>>(x, (const bf16x8*)wsB, wsL, ntok);
    router_k<<<ntok / 4, 256, 0, stream>>>(wsL, x, gateW, secret, out, ntok);
}

// Round 7
// 111.110 us; speedup vs baseline: 2.6827x; 1.0552x over previous
//
#include <hip/hip_runtime.h>
#include <stdint.h>

// OKRRouter, split-bf16 MFMA, 3 slim kernels:
// K1 prep_b:   gate_W^T | secret -> bf16 hi/lo fragment-linear layout in ws (1 MB, L2-resident).
// K2 gemm_lds: 64 tokens/block (4 waves x 16-token tile, full K). B staged per K-step into
//              double-buffered LDS via global_load_lds(16B) and shared by all 4 waves;
//              A fp32 register-prefetched 1 step ahead; trunc-split; 3-term MFMA.
//              Writes 128 reduced fp32 logits/token to ws.
// K3 router_k: 1 wave/token; mask/top-2/softmax + margin-guarded exact fp32 recompute
//              (validated rounds 3-6).

#define DDIM 2048
#define NEXP 64
#define NT   64          // K steps of 32
#define NEG_INF  -1000000000.0f
#define MRG_RAW  0.04f
#define MRG_WM   0.15f

typedef __attribute__((ext_vector_type(8))) short bf16x8;
typedef __attribute__((ext_vector_type(4))) float f32x4;

union BFrag { bf16x8 v; uint32_t w[4]; uint4 q; };

// ---- RNE hi/lo split (prep_b only) ----
__device__ inline void split8_rne(const float* a, bf16x8* hi, bf16x8* lo) {
    BFrag h, l;
    #pragma unroll
    for (int p = 0; p < 4; ++p) {
        const uint32_t u0 = __float_as_uint(a[2*p]);
        const uint32_t u1 = __float_as_uint(a[2*p+1]);
        const uint32_t h0 = (u0 + 0x7FFFu + ((u0 >> 16) & 1u)) >> 16;
        const uint32_t h1 = (u1 + 0x7FFFu + ((u1 >> 16) & 1u)) >> 16;
        const float r0 = a[2*p]   - __uint_as_float(h0 << 16);
        const float r1 = a[2*p+1] - __uint_as_float(h1 << 16);
        const uint32_t v0 = __float_as_uint(r0);
        const uint32_t v1 = __float_as_uint(r1);
        const uint32_t l0 = (v0 + 0x7FFFu + ((v0 >> 16) & 1u)) >> 16;
        const uint32_t l1 = (v1 + 0x7FFFu + ((v1 >> 16) & 1u)) >> 16;
        h.w[p] = h0 | (h1 << 16);
        l.w[p] = l0 | (l1 << 16);
    }
    *hi = h.v; *lo = l.v;
}

// ---- cheap truncation split for the A stream (validated rounds 4-6) ----
__device__ inline void split8t(const float* a, bf16x8* hi, bf16x8* lo) {
    BFrag h, l;
    #pragma unroll
    for (int p = 0; p < 4; ++p) {
        const uint32_t u0 = __float_as_uint(a[2*p]);
        const uint32_t u1 = __float_as_uint(a[2*p+1]);
        h.w[p] = (u0 >> 16) | (u1 & 0xFFFF0000u);
        const float r0 = a[2*p]   - __uint_as_float(u0 & 0xFFFF0000u);
        const float r1 = a[2*p+1] - __uint_as_float(u1 & 0xFFFF0000u);
        l.w[p] = (__float_as_uint(r0) >> 16) | (__float_as_uint(r1) & 0xFFFF0000u);
    }
    *hi = h.v; *lo = l.v;
}

// ---- K1: B' fragments. frag f = kstep*8+s is 128 slots of 16B: 64 lanes hi, 64 lanes lo.
// lane l holds B[kstep*32 + (l>>4)*8 + j][s*16 + (l&15)], j=0..7
__global__ void prep_b(const float* __restrict__ gateW, const float* __restrict__ secret,
                       uint4* __restrict__ wsB) {
    const int kstep = blockIdx.x;            // 0..63
    const int s = threadIdx.x >> 6;          // 0..7
    const int l = threadIdx.x & 63;
    const int col = s * 16 + (l & 15);
    const int kb  = kstep * 32 + (l >> 4) * 8;
    float v[8];
    if (col < NEXP) {
        #pragma unroll
        for (int j = 0; j < 8; ++j) v[j] = gateW[(size_t)col * DDIM + kb + j];
    } else {
        #pragma unroll
        for (int j = 0; j < 8; ++j) v[j] = secret[(size_t)(kb + j) * NEXP + (col - NEXP)];
    }
    bf16x8 hi, lo; split8_rne(v, &hi, &lo);
    const size_t base = (size_t)(kstep * 8 + s) * 128 + l;
    BFrag t;
    t.v = hi; wsB[base]      = t.q;
    t.v = lo; wsB[base + 64] = t.q;
}

// ---- async global->LDS, 16B per lane ----
__device__ inline void gl_lds16(const char* g, char* l) {
    __builtin_amdgcn_global_load_lds(
        (const __attribute__((address_space(1))) void*)g,
        (__attribute__((address_space(3))) void*)l, 16, 0, 0);
}

// ---- K2: GEMM, LDS-staged B (double-buffered), full K per wave ----
__global__ __launch_bounds__(256, 1)
void gemm_lds(const float* __restrict__ x, const char* __restrict__ wsB,
              float* __restrict__ wsL, int ntok)
{
    __shared__ __align__(16) char lds[2][16384];

    const int tid = threadIdx.x;
    const int w = tid >> 6, l = tid & 63;
    const int c = l & 15;          // token within 16-tile / frag col
    const int g = l >> 4;          // k-group / C-row group
    const int rowbase = blockIdx.x * 64 + w * 16;

    f32x4 acc[8];
    #pragma unroll
    for (int s = 0; s < 8; ++s) acc[s] = (f32x4){0.f, 0.f, 0.f, 0.f};

    const float* xr = x + (size_t)(rowbase + c) * DDIM + g * 8;

    // stage K-step ts into buffer buf: 16 frags x 1 KB; wave w DMAs frags {j*4+w}
    // (wave-uniform LDS base + lane*16 — required layout for global_load_lds)
    #define STAGE(ts, buf)                                                        \
        {                                                                         \
            _Pragma("unroll")                                                     \
            for (int j = 0; j < 4; ++j) {                                         \
                const int f = j * 4 + w;                                          \
                const int s_ = f >> 1, hl = f & 1;                                \
                gl_lds16(wsB + ((size_t)((ts) * 8 + s_) * 128 + hl * 64 + l) * 16,\
                         &lds[buf][f * 1024 + l * 16]);                           \
            }                                                                     \
        }

    float4 A0a, A0b, A1a, A1b;
    STAGE(0, 0);
    A0a = *reinterpret_cast<const float4*>(xr);
    A0b = *reinterpret_cast<const float4*>(xr + 4);

    for (int ts = 0; ts < NT; ++ts) {
        __syncthreads();   // drains vmcnt: stage(ts) + A-prefetch visible; buf^1 readers done

        if (ts < NT - 1) {
            STAGE(ts + 1, (ts + 1) & 1);
            A1a = *reinterpret_cast<const float4*>(xr + (ts + 1) * 32);
            A1b = *reinterpret_cast<const float4*>(xr + (ts + 1) * 32 + 4);
        }

        const float va[8] = {A0a.x, A0a.y, A0a.z, A0a.w, A0b.x, A0b.y, A0b.z, A0b.w};
        bf16x8 ah, al;
        split8t(va, &ah, &al);

        const char* bb = lds[ts & 1];
        #pragma unroll
        for (int s = 0; s < 8; ++s) {
            const bf16x8 bh = *reinterpret_cast<const bf16x8*>(bb + (2*s)     * 1024 + l * 16);
            const bf16x8 bl = *reinterpret_cast<const bf16x8*>(bb + (2*s + 1) * 1024 + l * 16);
            acc[s] = __builtin_amdgcn_mfma_f32_16x16x32_bf16(ah, bh, acc[s], 0, 0, 0);
            acc[s] = __builtin_amdgcn_mfma_f32_16x16x32_bf16(ah, bl, acc[s], 0, 0, 0);
            acc[s] = __builtin_amdgcn_mfma_f32_16x16x32_bf16(al, bh, acc[s], 0, 0, 0);
        }
        A0a = A1a; A0b = A1b;
    }
    #undef STAGE

    // C/D layout: row = (l>>4)*4 + reg, col = l&15
    #pragma unroll
    for (int s = 0; s < 8; ++s)
        #pragma unroll
        for (int r = 0; r < 4; ++r)
            wsL[(size_t)(rowbase + g * 4 + r) * 128 + s * 16 + c] = acc[s][r];
}

// ---- K3: router, 1 wave per token (validated round 6) ----
__global__ __launch_bounds__(256, 4)
void router_k(const float* __restrict__ wsL,
              const float* __restrict__ x,
              const float* __restrict__ gateW,
              const float* __restrict__ secret,
              float* __restrict__ out, int ntok)
{
    const int t = blockIdx.x * 4 + (threadIdx.x >> 6);
    const int e = threadIdx.x & 63;

    float raw = wsL[(size_t)t * 128 + e];
    float wm  = wsL[(size_t)t * 128 + NEXP + e];

    float rmax = raw;
    #pragma unroll
    for (int off = 32; off; off >>= 1) rmax = fmaxf(rmax, __shfl_xor(rmax, off));

    // guard 1: safe-mask boundary margin -> exact fp32 raw recompute (whole token)
    if (__any(fabsf(raw - (rmax - 1.5f)) < MRG_RAW)) {
        float s0 = 0.f, s1 = 0.f, s2 = 0.f, s3 = 0.f;
        const float4* xr = reinterpret_cast<const float4*>(x + (size_t)t * DDIM);
        const float4* wr = reinterpret_cast<const float4*>(gateW + (size_t)e * DDIM);
        for (int k = 0; k < DDIM / 4; ++k) {
            const float4 a = xr[k], b = wr[k];
            s0 = fmaf(a.x, b.x, s0); s1 = fmaf(a.y, b.y, s1);
            s2 = fmaf(a.z, b.z, s2); s3 = fmaf(a.w, b.w, s3);
        }
        raw = (s0 + s1) + (s2 + s3);
        rmax = raw;
        #pragma unroll
        for (int off = 32; off; off >>= 1) rmax = fmaxf(rmax, __shfl_xor(rmax, off));
    }

    const bool safe = (raw >= rmax - 1.5f);
    float m = safe ? wm : NEG_INF;

    // top-3 (value desc, lowest index on ties = jax.lax.top_k)
    float v1 = m; int e1 = e;
    #pragma unroll
    for (int off = 32; off; off >>= 1) {
        const float ov = __shfl_xor(v1, off); const int oi = __shfl_xor(e1, off);
        if (ov > v1 || (ov == v1 && oi < e1)) { v1 = ov; e1 = oi; }
    }
    float v2 = (e == e1) ? -3.0e38f : m; int e2 = e;
    #pragma unroll
    for (int off = 32; off; off >>= 1) {
        const float ov = __shfl_xor(v2, off); const int oi = __shfl_xor(e2, off);
        if (ov > v2 || (ov == v2 && oi < e2)) { v2 = ov; e2 = oi; }
    }
    float v3 = (e == e1 || e == e2) ? -3.0e38f : m; int e3 = e;
    #pragma unroll
    for (int off = 32; off; off >>= 1) {
        const float ov = __shfl_xor(v3, off); const int oi = __shfl_xor(e3, off);
        if (ov > v3 || (ov == v3 && oi < e3)) { v3 = ov; e3 = oi; }
    }

    // guard 2: close wm ordering among safe candidates -> exact fp32 wm recompute
    const bool wmRisk = (v2 > NEG_INF + 1.0f && v1 - v2 < MRG_WM) ||
                        (v3 > NEG_INF + 1.0f && v2 - v3 < MRG_WM);
    if (__any(wmRisk)) {
        float s0 = 0.f, s1 = 0.f, s2 = 0.f, s3 = 0.f;
        const float* xr = x + (size_t)t * DDIM;
        for (int k = 0; k < DDIM; k += 4) {
            s0 = fmaf(xr[k + 0], secret[(size_t)(k + 0) * NEXP + e], s0);
            s1 = fmaf(xr[k + 1], secret[(size_t)(k + 1) * NEXP + e], s1);
            s2 = fmaf(xr[k + 2], secret[(size_t)(k + 2) * NEXP + e], s2);
            s3 = fmaf(xr[k + 3], secret[(size_t)(k + 3) * NEXP + e], s3);
        }
        m = safe ? ((s0 + s1) + (s2 + s3)) : NEG_INF;
        v1 = m; e1 = e;
        #pragma unroll
        for (int off = 32; off; off >>= 1) {
            const float ov = __shfl_xor(v1, off); const int oi = __shfl_xor(e1, off);
            if (ov > v1 || (ov == v1 && oi < e1)) { v1 = ov; e1 = oi; }
        }
        v2 = (e == e1) ? -3.0e38f : m; e2 = e;
        #pragma unroll
        for (int off = 32; off; off >>= 1) {
            const float ov = __shfl_xor(v2, off); const int oi = __shfl_xor(e2, off);
            if (ov > v2 || (ov == v2 && oi < e2)) { v2 = ov; e2 = oi; }
        }
    }

    const float l1 = __shfl(raw, e1);
    const float l2 = __shfl(raw, e2);

    if (e == 0) {
        const float mm = fmaxf(l1, l2);
        const float x1 = expf(l1 - mm), x2 = expf(l2 - mm);
        const float inv = 1.0f / (x1 + x2);
        out[(size_t)t * 2 + 0] = x1 * inv;
        out[(size_t)t * 2 + 1] = x2 * inv;
        out[(size_t)2 * ntok + t * 2 + 0] = (float)e1;
        out[(size_t)2 * ntok + t * 2 + 1] = (float)e2;
    }
}

extern "C" void kernel_launch(void* const* d_in, const int* in_sizes, int n_in,
                              void* d_out, int out_size, void* d_ws, size_t ws_size,
                              hipStream_t stream) {
    const float* x      = (const float*)d_in[0];
    const float* gateW  = (const float*)d_in[1];
    const float* secret = (const float*)d_in[2];
    float* out = (float*)d_out;

    const int ntok = in_sizes[0] / DDIM;                 // 16384
    uint4* wsB = (uint4*)d_ws;                           // 1 MB fragments
    float* wsL = (float*)((char*)d_ws + (2u << 20));     // 8 MB logits [ntok][128]

    prep_b<<<64, 512, 0, stream>>>(gateW, secret, wsB);
    gemm_lds<<<ntok / 64, 256, 0, stream>>>(x, (const char*)wsB, wsL, ntok);
    router_k<<<ntok / 4, 256, 0, stream>>>(wsL, x, gateW, secret, out, ntok);
}

// Round 8
// 97.956 us; speedup vs baseline: 3.0429x; 1.1343x over previous
//
#include <hip/hip_runtime.h>
#include <stdint.h>

// OKRRouter, split-bf16 MFMA, 3 slim kernels:
// K1 prep_b:   gate_W^T | secret -> bf16 hi/lo fragment-linear layout in ws (1 MB, L2-resident).
// K2 gemm_lds: 32 tokens/block, 4 waves = 2 token-stripes x 2 K-halves (in-block split-K=2).
//              Per K-step both halves' B fragments staged into double-buffered LDS via
//              global_load_lds(16B), shared by the 2 stripe-waves of each half; A fp32
//              register-prefetched 1 step ahead; trunc-split; 3-term MFMA. LDS reduction
//              of the halves; writes 128 reduced fp32 logits/token to ws.
//              Grid 512 = 2 blocks/CU = 2 waves/SIMD (occupancy fix vs round 7).
// K3 router_k: 1 wave/token; mask/top-2/softmax + margin-guarded exact fp32 recompute
//              (validated rounds 3-7).

#define DDIM 2048
#define NEXP 64
#define NT   32          // K steps of 32 per half
#define NEG_INF  -1000000000.0f
#define MRG_RAW  0.04f
#define MRG_WM   0.15f
#define RST      130     // reduction row stride (floats)

typedef __attribute__((ext_vector_type(8))) short bf16x8;
typedef __attribute__((ext_vector_type(4))) float f32x4;

union BFrag { bf16x8 v; uint32_t w[4]; uint4 q; };

// ---- RNE hi/lo split (prep_b only) ----
__device__ inline void split8_rne(const float* a, bf16x8* hi, bf16x8* lo) {
    BFrag h, l;
    #pragma unroll
    for (int p = 0; p < 4; ++p) {
        const uint32_t u0 = __float_as_uint(a[2*p]);
        const uint32_t u1 = __float_as_uint(a[2*p+1]);
        const uint32_t h0 = (u0 + 0x7FFFu + ((u0 >> 16) & 1u)) >> 16;
        const uint32_t h1 = (u1 + 0x7FFFu + ((u1 >> 16) & 1u)) >> 16;
        const float r0 = a[2*p]   - __uint_as_float(h0 << 16);
        const float r1 = a[2*p+1] - __uint_as_float(h1 << 16);
        const uint32_t v0 = __float_as_uint(r0);
        const uint32_t v1 = __float_as_uint(r1);
        const uint32_t l0 = (v0 + 0x7FFFu + ((v0 >> 16) & 1u)) >> 16;
        const uint32_t l1 = (v1 + 0x7FFFu + ((v1 >> 16) & 1u)) >> 16;
        h.w[p] = h0 | (h1 << 16);
        l.w[p] = l0 | (l1 << 16);
    }
    *hi = h.v; *lo = l.v;
}

// ---- cheap truncation split for the A stream (validated rounds 4-7) ----
__device__ inline void split8t(const float* a, bf16x8* hi, bf16x8* lo) {
    BFrag h, l;
    #pragma unroll
    for (int p = 0; p < 4; ++p) {
        const uint32_t u0 = __float_as_uint(a[2*p]);
        const uint32_t u1 = __float_as_uint(a[2*p+1]);
        h.w[p] = (u0 >> 16) | (u1 & 0xFFFF0000u);
        const float r0 = a[2*p]   - __uint_as_float(u0 & 0xFFFF0000u);
        const float r1 = a[2*p+1] - __uint_as_float(u1 & 0xFFFF0000u);
        l.w[p] = (__float_as_uint(r0) >> 16) | (__float_as_uint(r1) & 0xFFFF0000u);
    }
    *hi = h.v; *lo = l.v;
}

// ---- K1: B' fragments. frag-set fs (=kstep 0..63) is 16 KB; frag i=(s<<1|hl) is 1 KB.
// lane l of frag (fs,s,hl) holds B[fs*32 + (l>>4)*8 + j][s*16 + (l&15)] (hi or lo), j=0..7
__global__ void prep_b(const float* __restrict__ gateW, const float* __restrict__ secret,
                       uint4* __restrict__ wsB) {
    const int kstep = blockIdx.x;            // 0..63
    const int s = threadIdx.x >> 6;          // 0..7
    const int l = threadIdx.x & 63;
    const int col = s * 16 + (l & 15);
    const int kb  = kstep * 32 + (l >> 4) * 8;
    float v[8];
    if (col < NEXP) {
        #pragma unroll
        for (int j = 0; j < 8; ++j) v[j] = gateW[(size_t)col * DDIM + kb + j];
    } else {
        #pragma unroll
        for (int j = 0; j < 8; ++j) v[j] = secret[(size_t)(kb + j) * NEXP + (col - NEXP)];
    }
    bf16x8 hi, lo; split8_rne(v, &hi, &lo);
    const size_t base = (size_t)(kstep * 8 + s) * 128 + l;
    BFrag t;
    t.v = hi; wsB[base]      = t.q;
    t.v = lo; wsB[base + 64] = t.q;
}

// ---- async global->LDS, 16B per lane ----
__device__ inline void gl_lds16(const char* g, char* l) {
    __builtin_amdgcn_global_load_lds(
        (const __attribute__((address_space(1))) void*)g,
        (__attribute__((address_space(3))) void*)l, 16, 0, 0);
}

// ---- K2: GEMM, in-block split-K=2, LDS-staged B (double-buffered) ----
__global__ __launch_bounds__(256, 2)
void gemm_lds(const float* __restrict__ x, const char* __restrict__ wsB,
              float* __restrict__ wsL, int ntok)
{
    __shared__ __align__(16) char lds[2][32768];   // [buf][half*16KB + frag*1KB + lane*16]

    const int tid = threadIdx.x;
    const int w = tid >> 6, l = tid & 63;
    const int p = w & 1;           // token stripe (16 tokens)
    const int h = w >> 1;          // K-half
    const int c = l & 15;          // token within tile / frag col
    const int g = l >> 4;          // k-group / C-row group
    const int rowbase = blockIdx.x * 32 + p * 16;

    f32x4 acc[8];
    #pragma unroll
    for (int s = 0; s < 8; ++s) acc[s] = (f32x4){0.f, 0.f, 0.f, 0.f};

    const float* xr = x + (size_t)(rowbase + c) * DDIM + h * 1024 + g * 8;

    // stage K-step ts (both halves, 32 frags x 1 KB); wave w DMAs frags {j*4+w}
    // (wave-uniform LDS base + lane*16 — required layout for global_load_lds)
    #define STAGE(ts, buf)                                                          \
        {                                                                           \
            _Pragma("unroll")                                                       \
            for (int j = 0; j < 8; ++j) {                                           \
                const int F  = j * 4 + w;            /* 0..31 */                    \
                const int fs = ((F >> 4) << 5) + (ts);                              \
                const int i  = F & 15;                                              \
                gl_lds16(wsB + ((size_t)(fs * 8 + (i >> 1)) * 128                   \
                                + (i & 1) * 64 + l) * 16,                           \
                         &lds[buf][F * 1024 + l * 16]);                             \
            }                                                                       \
        }

    float4 A0a, A0b, A1a, A1b;
    STAGE(0, 0);
    A0a = *reinterpret_cast<const float4*>(xr);
    A0b = *reinterpret_cast<const float4*>(xr + 4);

    for (int ts = 0; ts < NT; ++ts) {
        __syncthreads();   // drains own vmcnt: stage(ts)+A visible; buf^1 readers done

        if (ts < NT - 1) {
            STAGE(ts + 1, (ts + 1) & 1);
            A1a = *reinterpret_cast<const float4*>(xr + (ts + 1) * 32);
            A1b = *reinterpret_cast<const float4*>(xr + (ts + 1) * 32 + 4);
        }

        const float va[8] = {A0a.x, A0a.y, A0a.z, A0a.w, A0b.x, A0b.y, A0b.z, A0b.w};
        bf16x8 ah, al;
        split8t(va, &ah, &al);

        const char* bb = lds[ts & 1] + h * 16384;
        #pragma unroll
        for (int s = 0; s < 8; ++s) {
            const bf16x8 bh = *reinterpret_cast<const bf16x8*>(bb + (2*s)     * 1024 + l * 16);
            const bf16x8 bl = *reinterpret_cast<const bf16x8*>(bb + (2*s + 1) * 1024 + l * 16);
            acc[s] = __builtin_amdgcn_mfma_f32_16x16x32_bf16(ah, bh, acc[s], 0, 0, 0);
            acc[s] = __builtin_amdgcn_mfma_f32_16x16x32_bf16(ah, bl, acc[s], 0, 0, 0);
            acc[s] = __builtin_amdgcn_mfma_f32_16x16x32_bf16(al, bh, acc[s], 0, 0, 0);
        }
        A0a = A1a; A0b = A1b;
    }
    #undef STAGE

    // ---- reduce the 2 K-halves via LDS (overlay staging buffers) ----
    // C/D layout: row = (l>>4)*4 + reg, col = l&15
    float* red = reinterpret_cast<float*>(&lds[0][0]);   // [2 stripes][16 rows][RST]
    __syncthreads();
    if (h == 1) {
        float* L = red + p * 16 * RST;
        #pragma unroll
        for (int s = 0; s < 8; ++s)
            #pragma unroll
            for (int r = 0; r < 4; ++r)
                L[(g * 4 + r) * RST + s * 16 + c] = acc[s][r];
    }
    __syncthreads();
    if (h == 0) {
        const float* L = red + p * 16 * RST;
        #pragma unroll
        for (int s = 0; s < 8; ++s)
            #pragma unroll
            for (int r = 0; r < 4; ++r) {
                const float v = acc[s][r] + L[(g * 4 + r) * RST + s * 16 + c];
                wsL[(size_t)(rowbase + g * 4 + r) * 128 + s * 16 + c] = v;
            }
    }
}

// ---- K3: router, 1 wave per token (validated rounds 6-7) ----
__global__ __launch_bounds__(256, 4)
void router_k(const float* __restrict__ wsL,
              const float* __restrict__ x,
              const float* __restrict__ gateW,
              const float* __restrict__ secret,
              float* __restrict__ out, int ntok)
{
    const int t = blockIdx.x * 4 + (threadIdx.x >> 6);
    const int e = threadIdx.x & 63;

    float raw = wsL[(size_t)t * 128 + e];
    float wm  = wsL[(size_t)t * 128 + NEXP + e];

    float rmax = raw;
    #pragma unroll
    for (int off = 32; off; off >>= 1) rmax = fmaxf(rmax, __shfl_xor(rmax, off));

    // guard 1: safe-mask boundary margin -> exact fp32 raw recompute (whole token)
    if (__any(fabsf(raw - (rmax - 1.5f)) < MRG_RAW)) {
        float s0 = 0.f, s1 = 0.f, s2 = 0.f, s3 = 0.f;
        const float4* xr = reinterpret_cast<const float4*>(x + (size_t)t * DDIM);
        const float4* wr = reinterpret_cast<const float4*>(gateW + (size_t)e * DDIM);
        for (int k = 0; k < DDIM / 4; ++k) {
            const float4 a = xr[k], b = wr[k];
            s0 = fmaf(a.x, b.x, s0); s1 = fmaf(a.y, b.y, s1);
            s2 = fmaf(a.z, b.z, s2); s3 = fmaf(a.w, b.w, s3);
        }
        raw = (s0 + s1) + (s2 + s3);
        rmax = raw;
        #pragma unroll
        for (int off = 32; off; off >>= 1) rmax = fmaxf(rmax, __shfl_xor(rmax, off));
    }

    const bool safe = (raw >= rmax - 1.5f);
    float m = safe ? wm : NEG_INF;

    // top-3 (value desc, lowest index on ties = jax.lax.top_k)
    float v1 = m; int e1 = e;
    #pragma unroll
    for (int off = 32; off; off >>= 1) {
        const float ov = __shfl_xor(v1, off); const int oi = __shfl_xor(e1, off);
        if (ov > v1 || (ov == v1 && oi < e1)) { v1 = ov; e1 = oi; }
    }
    float v2 = (e == e1) ? -3.0e38f : m; int e2 = e;
    #pragma unroll
    for (int off = 32; off; off >>= 1) {
        const float ov = __shfl_xor(v2, off); const int oi = __shfl_xor(e2, off);
        if (ov > v2 || (ov == v2 && oi < e2)) { v2 = ov; e2 = oi; }
    }
    float v3 = (e == e1 || e == e2) ? -3.0e38f : m; int e3 = e;
    #pragma unroll
    for (int off = 32; off; off >>= 1) {
        const float ov = __shfl_xor(v3, off); const int oi = __shfl_xor(e3, off);
        if (ov > v3 || (ov == v3 && oi < e3)) { v3 = ov; e3 = oi; }
    }

    // guard 2: close wm ordering among safe candidates -> exact fp32 wm recompute
    const bool wmRisk = (v2 > NEG_INF + 1.0f && v1 - v2 < MRG_WM) ||
                        (v3 > NEG_INF + 1.0f && v2 - v3 < MRG_WM);
    if (__any(wmRisk)) {
        float s0 = 0.f, s1 = 0.f, s2 = 0.f, s3 = 0.f;
        const float* xr = x + (size_t)t * DDIM;
        for (int k = 0; k < DDIM; k += 4) {
            s0 = fmaf(xr[k + 0], secret[(size_t)(k + 0) * NEXP + e], s0);
            s1 = fmaf(xr[k + 1], secret[(size_t)(k + 1) * NEXP + e], s1);
            s2 = fmaf(xr[k + 2], secret[(size_t)(k + 2) * NEXP + e], s2);
            s3 = fmaf(xr[k + 3], secret[(size_t)(k + 3) * NEXP + e], s3);
        }
        m = safe ? ((s0 + s1) + (s2 + s3)) : NEG_INF;
        v1 = m; e1 = e;
        #pragma unroll
        for (int off = 32; off; off >>= 1) {
            const float ov = __shfl_xor(v1, off); const int oi = __shfl_xor(e1, off);
            if (ov > v1 || (ov == v1 && oi < e1)) { v1 = ov; e1 = oi; }
        }
        v2 = (e == e1) ? -3.0e38f : m; e2 = e;
        #pragma unroll
        for (int off = 32; off; off >>= 1) {
            const float ov = __shfl_xor(v2, off); const int oi = __shfl_xor(e2, off);
            if (ov > v2 || (ov == v2 && oi < e2)) { v2 = ov; e2 = oi; }
        }
    }

    const float l1 = __shfl(raw, e1);
    const float l2 = __shfl(raw, e2);

    if (e == 0) {
        const float mm = fmaxf(l1, l2);
        const float x1 = expf(l1 - mm), x2 = expf(l2 - mm);
        const float inv = 1.0f / (x1 + x2);
        out[(size_t)t * 2 + 0] = x1 * inv;
        out[(size_t)t * 2 + 1] = x2 * inv;
        out[(size_t)2 * ntok + t * 2 + 0] = (float)e1;
        out[(size_t)2 * ntok + t * 2 + 1] = (float)e2;
    }
}

extern "C" void kernel_launch(void* const* d_in, const int* in_sizes, int n_in,
                              void* d_out, int out_size, void* d_ws, size_t ws_size,
                              hipStream_t stream) {
    const float* x      = (const float*)d_in[0];
    const float* gateW  = (const float*)d_in[1];
    const float* secret = (const float*)d_in[2];
    float* out = (float*)d_out;

    const int ntok = in_sizes[0] / DDIM;                 // 16384
    uint4* wsB = (uint4*)d_ws;                           // 1 MB fragments
    float* wsL = (float*)((char*)d_ws + (2u << 20));     // 8 MB logits [ntok][128]

    prep_b<<<64, 512, 0, stream>>>(gateW, secret, wsB);
    gemm_lds<<<ntok / 32, 256, 0, stream>>>(x, (const char*)wsB, wsL, ntok);
    router_k<<<ntok / 4, 256, 0, stream>>>(wsL, x, gateW, secret, out, ntok);
}

// Round 9
// 94.843 us; speedup vs baseline: 3.1428x; 1.0328x over previous
//
#include <hip/hip_runtime.h>
#include <stdint.h>

// OKRRouter, split-bf16 MFMA, 3 slim kernels:
// K1 prep_b:  gate_W^T | secret -> bf16 hi/lo fragment-linear layout in ws (1 MB, L2-resident).
// K2 gemm_q:  grid split-K=4. Block = 256 thr = 4 waves = 4 token-tiles (64 tokens), one
//             K-quarter per block -> 4 blocks/CU, 16 waves/CU (4/SIMD). B staged per K-step
//             into double-buffered 16 KB LDS via global_load_lds(16B); 2-phase recipe order:
//             issue next-step STAGE+A first, vmcnt(0) only AFTER the MFMA cluster, raw
//             s_barrier. fp32 partials [4][ntok][128] -> ws.
// K3 router_k: 1 wave/token; sums 4 partials; mask/top-2/softmax + margin-guarded exact
//             fp32 recompute (validated rounds 3-8).

#define DDIM 2048
#define NEXP 64
#define NEG_INF  -1000000000.0f
#define MRG_RAW  0.04f
#define MRG_WM   0.15f

typedef __attribute__((ext_vector_type(8))) short bf16x8;
typedef __attribute__((ext_vector_type(4))) float f32x4;

union BFrag { bf16x8 v; uint32_t w[4]; uint4 q; };

// ---- RNE hi/lo split (prep_b only) ----
__device__ inline void split8_rne(const float* a, bf16x8* hi, bf16x8* lo) {
    BFrag h, l;
    #pragma unroll
    for (int p = 0; p < 4; ++p) {
        const uint32_t u0 = __float_as_uint(a[2*p]);
        const uint32_t u1 = __float_as_uint(a[2*p+1]);
        const uint32_t h0 = (u0 + 0x7FFFu + ((u0 >> 16) & 1u)) >> 16;
        const uint32_t h1 = (u1 + 0x7FFFu + ((u1 >> 16) & 1u)) >> 16;
        const float r0 = a[2*p]   - __uint_as_float(h0 << 16);
        const float r1 = a[2*p+1] - __uint_as_float(h1 << 16);
        const uint32_t v0 = __float_as_uint(r0);
        const uint32_t v1 = __float_as_uint(r1);
        const uint32_t l0 = (v0 + 0x7FFFu + ((v0 >> 16) & 1u)) >> 16;
        const uint32_t l1 = (v1 + 0x7FFFu + ((v1 >> 16) & 1u)) >> 16;
        h.w[p] = h0 | (h1 << 16);
        l.w[p] = l0 | (l1 << 16);
    }
    *hi = h.v; *lo = l.v;
}

// ---- cheap truncation split for the A stream (validated rounds 4-8) ----
__device__ inline void split8t(const float* a, bf16x8* hi, bf16x8* lo) {
    BFrag h, l;
    #pragma unroll
    for (int p = 0; p < 4; ++p) {
        const uint32_t u0 = __float_as_uint(a[2*p]);
        const uint32_t u1 = __float_as_uint(a[2*p+1]);
        h.w[p] = (u0 >> 16) | (u1 & 0xFFFF0000u);
        const float r0 = a[2*p]   - __uint_as_float(u0 & 0xFFFF0000u);
        const float r1 = a[2*p+1] - __uint_as_float(u1 & 0xFFFF0000u);
        l.w[p] = (__float_as_uint(r0) >> 16) | (__float_as_uint(r1) & 0xFFFF0000u);
    }
    *hi = h.v; *lo = l.v;
}

// ---- K1: B' fragments. frag f = kstep*8+s is 128 slots of 16B: 64 lanes hi, 64 lanes lo.
// lane l holds B[kstep*32 + (l>>4)*8 + j][s*16 + (l&15)], j=0..7
__global__ void prep_b(const float* __restrict__ gateW, const float* __restrict__ secret,
                       uint4* __restrict__ wsB) {
    const int kstep = blockIdx.x;            // 0..63
    const int s = threadIdx.x >> 6;          // 0..7
    const int l = threadIdx.x & 63;
    const int col = s * 16 + (l & 15);
    const int kb  = kstep * 32 + (l >> 4) * 8;
    float v[8];
    if (col < NEXP) {
        #pragma unroll
        for (int j = 0; j < 8; ++j) v[j] = gateW[(size_t)col * DDIM + kb + j];
    } else {
        #pragma unroll
        for (int j = 0; j < 8; ++j) v[j] = secret[(size_t)(kb + j) * NEXP + (col - NEXP)];
    }
    bf16x8 hi, lo; split8_rne(v, &hi, &lo);
    const size_t base = (size_t)(kstep * 8 + s) * 128 + l;
    BFrag t;
    t.v = hi; wsB[base]      = t.q;
    t.v = lo; wsB[base + 64] = t.q;
}

// ---- async global->LDS, 16B per lane ----
__device__ inline void gl_lds16(const char* g, char* l) {
    __builtin_amdgcn_global_load_lds(
        (const __attribute__((address_space(1))) void*)g,
        (__attribute__((address_space(3))) void*)l, 16, 0, 0);
}

// ---- K2: GEMM, grid split-K, 4 blocks/CU, 2-phase-recipe loop ----
template <int KSPLIT>
__global__ __launch_bounds__(256, 4)
void gemm_q(const float* __restrict__ x, const char* __restrict__ wsB,
            float* __restrict__ wsP, int ntok)
{
    const int NTS = (DDIM / KSPLIT) / 32;          // ksteps per block
    __shared__ __align__(16) char lds[2][16384];   // dbuf: 16 frags x 1 KB

    const int tid = threadIdx.x;
    const int w = tid >> 6, l = tid & 63;
    const int c = l & 15;          // token within tile / frag col
    const int g = l >> 4;          // k-group / C-row group
    const int q  = blockIdx.x & (KSPLIT - 1);
    const int mb = blockIdx.x / KSPLIT;
    const int rowbase = mb * 64 + w * 16;

    f32x4 acc[8];
    #pragma unroll
    for (int s = 0; s < 8; ++s) acc[s] = (f32x4){0.f, 0.f, 0.f, 0.f};

    const float* xr = x + (size_t)(rowbase + c) * DDIM + q * (DDIM / KSPLIT) + g * 8;
    const char*  bq = wsB + (size_t)(q * NTS) * 16384;   // this quarter's frag-sets

    // stage kstep ts into buf: 16 frags x 1 KB; thread stages frags {j*4+w}, slot l.
    // (wave-uniform LDS base + lane*16 — required layout for global_load_lds)
    #define STAGE(ts, buf)                                                       \
        {                                                                        \
            _Pragma("unroll")                                                    \
            for (int j = 0; j < 4; ++j) {                                        \
                const int i = j * 4 + w;                                         \
                gl_lds16(bq + ((size_t)((ts) * 8 + (i >> 1)) * 128               \
                               + (i & 1) * 64 + l) * 16,                         \
                         &lds[buf][i * 1024 + l * 16]);                          \
            }                                                                    \
        }

    float4 A0a, A0b, A1a, A1b;
    STAGE(0, 0);
    A0a = *reinterpret_cast<const float4*>(xr);
    A0b = *reinterpret_cast<const float4*>(xr + 4);
    asm volatile("s_waitcnt vmcnt(0)" ::: "memory");
    __builtin_amdgcn_s_barrier();

    #pragma unroll 1
    for (int ts = 0; ts < NTS; ++ts) {
        const int cur = ts & 1;
        // issue next step's loads FIRST; they retire during the MFMA cluster below.
        // WAR-safe: lds[cur^1] was last ds_read at step ts-1, finished before the
        // barrier every wave just passed.
        if (ts + 1 < NTS) {
            STAGE(ts + 1, cur ^ 1);
            A1a = *reinterpret_cast<const float4*>(xr + (ts + 1) * 32);
            A1b = *reinterpret_cast<const float4*>(xr + (ts + 1) * 32 + 4);
        }

        const float va[8] = {A0a.x, A0a.y, A0a.z, A0a.w, A0b.x, A0b.y, A0b.z, A0b.w};
        bf16x8 ah, al;
        split8t(va, &ah, &al);

        const char* bb = lds[cur];
        #pragma unroll
        for (int s = 0; s < 8; ++s) {
            const bf16x8 bh = *reinterpret_cast<const bf16x8*>(bb + (2*s)     * 1024 + l * 16);
            const bf16x8 bl = *reinterpret_cast<const bf16x8*>(bb + (2*s + 1) * 1024 + l * 16);
            acc[s] = __builtin_amdgcn_mfma_f32_16x16x32_bf16(ah, bh, acc[s], 0, 0, 0);
            acc[s] = __builtin_amdgcn_mfma_f32_16x16x32_bf16(ah, bl, acc[s], 0, 0, 0);
            acc[s] = __builtin_amdgcn_mfma_f32_16x16x32_bf16(al, bh, acc[s], 0, 0, 0);
        }

        // counted-drain point: next-step loads were issued ~24 MFMAs ago
        asm volatile("s_waitcnt vmcnt(0)" ::: "memory");
        __builtin_amdgcn_s_barrier();
        A0a = A1a; A0b = A1b;
    }
    #undef STAGE

    // partials: C/D layout row = (l>>4)*4 + reg, col = l&15
    const size_t MN = (size_t)ntok * 128;
    #pragma unroll
    for (int s = 0; s < 8; ++s)
        #pragma unroll
        for (int r = 0; r < 4; ++r)
            wsP[(size_t)q * MN + (size_t)(rowbase + g * 4 + r) * 128 + s * 16 + c] = acc[s][r];
}

// ---- K3: router, 1 wave per token, sums KSPLIT partials (validated rounds 2-8) ----
template <int KSPLIT>
__global__ __launch_bounds__(256, 4)
void router_k(const float* __restrict__ wsP,
              const float* __restrict__ x,
              const float* __restrict__ gateW,
              const float* __restrict__ secret,
              float* __restrict__ out, int ntok)
{
    const int t = blockIdx.x * 4 + (threadIdx.x >> 6);
    const int e = threadIdx.x & 63;
    const size_t MN = (size_t)ntok * 128;

    float raw = 0.f, wm = 0.f;
    #pragma unroll
    for (int q = 0; q < KSPLIT; ++q) {
        raw += wsP[(size_t)q * MN + (size_t)t * 128 + e];
        wm  += wsP[(size_t)q * MN + (size_t)t * 128 + NEXP + e];
    }

    float rmax = raw;
    #pragma unroll
    for (int off = 32; off; off >>= 1) rmax = fmaxf(rmax, __shfl_xor(rmax, off));

    // guard 1: safe-mask boundary margin -> exact fp32 raw recompute (whole token)
    if (__any(fabsf(raw - (rmax - 1.5f)) < MRG_RAW)) {
        float s0 = 0.f, s1 = 0.f, s2 = 0.f, s3 = 0.f;
        const float4* xr = reinterpret_cast<const float4*>(x + (size_t)t * DDIM);
        const float4* wr = reinterpret_cast<const float4*>(gateW + (size_t)e * DDIM);
        for (int k = 0; k < DDIM / 4; ++k) {
            const float4 a = xr[k], b = wr[k];
            s0 = fmaf(a.x, b.x, s0); s1 = fmaf(a.y, b.y, s1);
            s2 = fmaf(a.z, b.z, s2); s3 = fmaf(a.w, b.w, s3);
        }
        raw = (s0 + s1) + (s2 + s3);
        rmax = raw;
        #pragma unroll
        for (int off = 32; off; off >>= 1) rmax = fmaxf(rmax, __shfl_xor(rmax, off));
    }

    const bool safe = (raw >= rmax - 1.5f);
    float m = safe ? wm : NEG_INF;

    // top-3 (value desc, lowest index on ties = jax.lax.top_k)
    float v1 = m; int e1 = e;
    #pragma unroll
    for (int off = 32; off; off >>= 1) {
        const float ov = __shfl_xor(v1, off); const int oi = __shfl_xor(e1, off);
        if (ov > v1 || (ov == v1 && oi < e1)) { v1 = ov; e1 = oi; }
    }
    float v2 = (e == e1) ? -3.0e38f : m; int e2 = e;
    #pragma unroll
    for (int off = 32; off; off >>= 1) {
        const float ov = __shfl_xor(v2, off); const int oi = __shfl_xor(e2, off);
        if (ov > v2 || (ov == v2 && oi < e2)) { v2 = ov; e2 = oi; }
    }
    float v3 = (e == e1 || e == e2) ? -3.0e38f : m; int e3 = e;
    #pragma unroll
    for (int off = 32; off; off >>= 1) {
        const float ov = __shfl_xor(v3, off); const int oi = __shfl_xor(e3, off);
        if (ov > v3 || (ov == v3 && oi < e3)) { v3 = ov; e3 = oi; }
    }

    // guard 2: close wm ordering among safe candidates -> exact fp32 wm recompute
    const bool wmRisk = (v2 > NEG_INF + 1.0f && v1 - v2 < MRG_WM) ||
                        (v3 > NEG_INF + 1.0f && v2 - v3 < MRG_WM);
    if (__any(wmRisk)) {
        float s0 = 0.f, s1 = 0.f, s2 = 0.f, s3 = 0.f;
        const float* xr = x + (size_t)t * DDIM;
        for (int k = 0; k < DDIM; k += 4) {
            s0 = fmaf(xr[k + 0], secret[(size_t)(k + 0) * NEXP + e], s0);
            s1 = fmaf(xr[k + 1], secret[(size_t)(k + 1) * NEXP + e], s1);
            s2 = fmaf(xr[k + 2], secret[(size_t)(k + 2) * NEXP + e], s2);
            s3 = fmaf(xr[k + 3], secret[(size_t)(k + 3) * NEXP + e], s3);
        }
        m = safe ? ((s0 + s1) + (s2 + s3)) : NEG_INF;
        v1 = m; e1 = e;
        #pragma unroll
        for (int off = 32; off; off >>= 1) {
            const float ov = __shfl_xor(v1, off); const int oi = __shfl_xor(e1, off);
            if (ov > v1 || (ov == v1 && oi < e1)) { v1 = ov; e1 = oi; }
        }
        v2 = (e == e1) ? -3.0e38f : m; e2 = e;
        #pragma unroll
        for (int off = 32; off; off >>= 1) {
            const float ov = __shfl_xor(v2, off); const int oi = __shfl_xor(e2, off);
            if (ov > v2 || (ov == v2 && oi < e2)) { v2 = ov; e2 = oi; }
        }
    }

    const float l1 = __shfl(raw, e1);
    const float l2 = __shfl(raw, e2);

    if (e == 0) {
        const float mm = fmaxf(l1, l2);
        const float x1 = expf(l1 - mm), x2 = expf(l2 - mm);
        const float inv = 1.0f / (x1 + x2);
        out[(size_t)t * 2 + 0] = x1 * inv;
        out[(size_t)t * 2 + 1] = x2 * inv;
        out[(size_t)2 * ntok + t * 2 + 0] = (float)e1;
        out[(size_t)2 * ntok + t * 2 + 1] = (float)e2;
    }
}

extern "C" void kernel_launch(void* const* d_in, const int* in_sizes, int n_in,
                              void* d_out, int out_size, void* d_ws, size_t ws_size,
                              hipStream_t stream) {
    const float* x      = (const float*)d_in[0];
    const float* gateW  = (const float*)d_in[1];
    const float* secret = (const float*)d_in[2];
    float* out = (float*)d_out;

    const int ntok = in_sizes[0] / DDIM;                 // 16384
    uint4* wsB = (uint4*)d_ws;                           // 1 MB fragments
    float* wsP = (float*)((char*)d_ws + (2u << 20));     // partials [KSPLIT][ntok][128]
    const size_t MN4 = (size_t)ntok * 128 * 4;

    prep_b<<<64, 512, 0, stream>>>(gateW, secret, wsB);

    if (ws_size >= (2u << 20) + 4 * MN4) {
        gemm_q<4><<<(ntok / 64) * 4, 256, 0, stream>>>(x, (const char*)wsB, wsP, ntok);
        router_k<4><<<ntok / 4, 256, 0, stream>>>(wsP, x, gateW, secret, out, ntok);
    } else {
        gemm_q<1><<<(ntok / 64), 256, 0, stream>>>(x, (const char*)wsB, wsP, ntok);
        router_k<1><<<ntok / 4, 256, 0, stream>>>(wsP, x, gateW, secret, out, ntok);
    }
}

// Round 10
// 94.757 us; speedup vs baseline: 3.1456x; 1.0009x over previous
//
#include <hip/hip_runtime.h>
#include <stdint.h>

// OKRRouter, split-bf16 MFMA, 3 slim kernels:
// K1 prep_b:  gate_W^T | secret -> bf16 hi/lo fragment-linear layout in ws (1 MB, L2-resident).
// K2 gemm_p:  grid split-K=4; 512 thr = 8 waves = 128 tokens/block; 2 blocks/CU.
//             Per K-step stage 32 KB into double-buffered LDS via global_load_lds(16B) ONLY
//             (B fragments 16 KB + A tile 16 KB, A XOR-swizzled both-sides within 128B rows).
//             NO register-destined global loads in the loop -> compiler inserts no vmcnt
//             drains; single manual vmcnt(0) (4 own gl_lds, issued one full compute-window
//             earlier) + raw s_barrier per step (T3 minimum).
// K3 router_k: 1 wave/token; sums 4 partials; mask/top-2/softmax + margin-guarded exact
//             fp32 recompute (validated rounds 3-9).

#define DDIM 2048
#define NEXP 64
#define TOKB 128
#define KSPL 4
#define NTS  16          // (DDIM/KSPL)/32
#define NEG_INF  -1000000000.0f
#define MRG_RAW  0.04f
#define MRG_WM   0.15f

typedef __attribute__((ext_vector_type(8))) short bf16x8;
typedef __attribute__((ext_vector_type(4))) float f32x4;

union BFrag { bf16x8 v; uint32_t w[4]; uint4 q; };

// ---- RNE hi/lo split (prep_b only) ----
__device__ inline void split8_rne(const float* a, bf16x8* hi, bf16x8* lo) {
    BFrag h, l;
    #pragma unroll
    for (int p = 0; p < 4; ++p) {
        const uint32_t u0 = __float_as_uint(a[2*p]);
        const uint32_t u1 = __float_as_uint(a[2*p+1]);
        const uint32_t h0 = (u0 + 0x7FFFu + ((u0 >> 16) & 1u)) >> 16;
        const uint32_t h1 = (u1 + 0x7FFFu + ((u1 >> 16) & 1u)) >> 16;
        const float r0 = a[2*p]   - __uint_as_float(h0 << 16);
        const float r1 = a[2*p+1] - __uint_as_float(h1 << 16);
        const uint32_t v0 = __float_as_uint(r0);
        const uint32_t v1 = __float_as_uint(r1);
        const uint32_t l0 = (v0 + 0x7FFFu + ((v0 >> 16) & 1u)) >> 16;
        const uint32_t l1 = (v1 + 0x7FFFu + ((v1 >> 16) & 1u)) >> 16;
        h.w[p] = h0 | (h1 << 16);
        l.w[p] = l0 | (l1 << 16);
    }
    *hi = h.v; *lo = l.v;
}

// ---- cheap truncation split for the A stream (validated rounds 4-9) ----
__device__ inline void split8t(const float* a, bf16x8* hi, bf16x8* lo) {
    BFrag h, l;
    #pragma unroll
    for (int p = 0; p < 4; ++p) {
        const uint32_t u0 = __float_as_uint(a[2*p]);
        const uint32_t u1 = __float_as_uint(a[2*p+1]);
        h.w[p] = (u0 >> 16) | (u1 & 0xFFFF0000u);
        const float r0 = a[2*p]   - __uint_as_float(u0 & 0xFFFF0000u);
        const float r1 = a[2*p+1] - __uint_as_float(u1 & 0xFFFF0000u);
        l.w[p] = (__float_as_uint(r0) >> 16) | (__float_as_uint(r1) & 0xFFFF0000u);
    }
    *hi = h.v; *lo = l.v;
}

// ---- K1: B' fragments. frag f = kstep*8+s is 128 slots of 16B: 64 lanes hi, 64 lanes lo.
// lane l holds B[kstep*32 + (l>>4)*8 + j][s*16 + (l&15)], j=0..7
__global__ void prep_b(const float* __restrict__ gateW, const float* __restrict__ secret,
                       uint4* __restrict__ wsB) {
    const int kstep = blockIdx.x;            // 0..63
    const int s = threadIdx.x >> 6;          // 0..7
    const int l = threadIdx.x & 63;
    const int col = s * 16 + (l & 15);
    const int kb  = kstep * 32 + (l >> 4) * 8;
    float v[8];
    if (col < NEXP) {
        #pragma unroll
        for (int j = 0; j < 8; ++j) v[j] = gateW[(size_t)col * DDIM + kb + j];
    } else {
        #pragma unroll
        for (int j = 0; j < 8; ++j) v[j] = secret[(size_t)(kb + j) * NEXP + (col - NEXP)];
    }
    bf16x8 hi, lo; split8_rne(v, &hi, &lo);
    const size_t base = (size_t)(kstep * 8 + s) * 128 + l;
    BFrag t;
    t.v = hi; wsB[base]      = t.q;
    t.v = lo; wsB[base + 64] = t.q;
}

// ---- async global->LDS, 16B per lane ----
__device__ inline void gl_lds16(const char* g, char* l) {
    __builtin_amdgcn_global_load_lds(
        (const __attribute__((address_space(1))) void*)g,
        (__attribute__((address_space(3))) void*)l, 16, 0, 0);
}

// ---- K2: GEMM, everything staged via global_load_lds, counted single-wait loop ----
__global__ __launch_bounds__(512, 4)   // 4 waves/EU -> 2 blocks/CU (512 thr = 8 waves)
void gemm_p(const float* __restrict__ x, const char* __restrict__ wsB,
            float* __restrict__ wsP, int ntok)
{
    // per buffer: [0,16384) = 16 B-frags x 1 KB ; [16384,32768) = A tile 128 rows x 128 B
    __shared__ __align__(16) char lds[2][32768];

    const int tid = threadIdx.x;
    const int w = tid >> 6, l = tid & 63;
    const int c = l & 15;              // token within wave tile / frag col
    const int g = l >> 4;              // k-group / C-row group
    const int q  = blockIdx.x & (KSPL - 1);
    const int mb = blockIdx.x / KSPL;
    const int rowbase = mb * TOKB;     // block token base
    const int wrow = rowbase + w * 16; // wave token base

    f32x4 acc[8];
    #pragma unroll
    for (int s = 0; s < 8; ++s) acc[s] = (f32x4){0.f, 0.f, 0.f, 0.f};

    const char*  bq = wsB + (size_t)(q * NTS) * 16384;   // this quarter's B frag-sets
    const float* xq = x + q * (DDIM / KSPL);             // this quarter's K offset

    // stage step ts into buf: 2048 slots x 16B, 4 gl_lds16/thread.
    // B slots 0..1023: slot = i*64 + lane  (i = frag 0..15) — matches wsB layout.
    // A slots 1024..2047: a = slot-1024; row r = a>>3, col-grp cg = a&7;
    //   LDS slot (r,cg) holds SOURCE col-grp (cg ^ (r&7))  [XOR swizzle, within 128B row].
    #define STAGE(ts, buf)                                                         \
        {                                                                          \
            _Pragma("unroll")                                                      \
            for (int j = 0; j < 2; ++j) {                                          \
                const int slot = j * 512 + tid;                                    \
                const int i = slot >> 6;                                           \
                gl_lds16(bq + (size_t)(ts) * 16384 + i * 1024 + l * 16,            \
                         &lds[buf][slot * 16]);                                    \
            }                                                                      \
            _Pragma("unroll")                                                      \
            for (int j = 0; j < 2; ++j) {                                          \
                const int a = j * 512 + tid;                                       \
                const int r = a >> 3, cg = a & 7;                                  \
                const int scg = cg ^ (r & 7);                                      \
                gl_lds16((const char*)(xq + (size_t)(rowbase + r) * DDIM           \
                                       + (ts) * 32 + scg * 4),                     \
                         &lds[buf][16384 + a * 16]);                               \
            }                                                                      \
        }

    STAGE(0, 0);
    asm volatile("s_waitcnt vmcnt(0)" ::: "memory");
    __builtin_amdgcn_s_barrier();

    #pragma unroll 1
    for (int ts = 0; ts < NTS; ++ts) {
        const int cur = ts & 1;
        const int nts = (ts + 1 < NTS) ? ts + 1 : ts;   // clamped dummy restage at tail
        STAGE(nts, cur ^ 1);                            // issue next step FIRST (T3)

        // ---- A from LDS (swizzled read), split in-register ----
        const char* ab = &lds[cur][16384];
        const int r = w * 16 + c;
        const int s0 = (2 * g)     ^ (r & 7);
        const int s1 = (2 * g + 1) ^ (r & 7);
        const float4 fa = *reinterpret_cast<const float4*>(ab + r * 128 + s0 * 16);
        const float4 fb = *reinterpret_cast<const float4*>(ab + r * 128 + s1 * 16);
        const float va[8] = {fa.x, fa.y, fa.z, fa.w, fb.x, fb.y, fb.z, fb.w};
        bf16x8 ah, al;
        split8t(va, &ah, &al);

        // ---- B frags + MFMA ----
        const char* bb = lds[cur];
        #pragma unroll
        for (int s = 0; s < 8; ++s) {
            const bf16x8 bh = *reinterpret_cast<const bf16x8*>(bb + (2*s)     * 1024 + l * 16);
            const bf16x8 bl = *reinterpret_cast<const bf16x8*>(bb + (2*s + 1) * 1024 + l * 16);
            acc[s] = __builtin_amdgcn_mfma_f32_16x16x32_bf16(ah, bh, acc[s], 0, 0, 0);
            acc[s] = __builtin_amdgcn_mfma_f32_16x16x32_bf16(ah, bl, acc[s], 0, 0, 0);
            acc[s] = __builtin_amdgcn_mfma_f32_16x16x32_bf16(al, bh, acc[s], 0, 0, 0);
        }

        // own 4 gl_lds of STAGE(ts+1) are the only outstanding vmem ops; they were
        // issued one full compute-window ago -> near-zero stall. Then release buffers.
        asm volatile("s_waitcnt vmcnt(0)" ::: "memory");
        __builtin_amdgcn_s_barrier();
    }
    #undef STAGE

    // partials: C/D layout row = (l>>4)*4 + reg, col = l&15
    const size_t MN = (size_t)ntok * 128;
    #pragma unroll
    for (int s = 0; s < 8; ++s)
        #pragma unroll
        for (int r = 0; r < 4; ++r)
            wsP[(size_t)q * MN + (size_t)(wrow + g * 4 + r) * 128 + s * 16 + c] = acc[s][r];
}

// ---- K3: router, 1 wave per token, sums KSPLIT partials (validated rounds 2-9) ----
template <int KSPLIT>
__global__ __launch_bounds__(256, 4)
void router_k(const float* __restrict__ wsP,
              const float* __restrict__ x,
              const float* __restrict__ gateW,
              const float* __restrict__ secret,
              float* __restrict__ out, int ntok)
{
    const int t = blockIdx.x * 4 + (threadIdx.x >> 6);
    const int e = threadIdx.x & 63;
    const size_t MN = (size_t)ntok * 128;

    float raw = 0.f, wm = 0.f;
    #pragma unroll
    for (int q = 0; q < KSPLIT; ++q) {
        raw += wsP[(size_t)q * MN + (size_t)t * 128 + e];
        wm  += wsP[(size_t)q * MN + (size_t)t * 128 + NEXP + e];
    }

    float rmax = raw;
    #pragma unroll
    for (int off = 32; off; off >>= 1) rmax = fmaxf(rmax, __shfl_xor(rmax, off));

    // guard 1: safe-mask boundary margin -> exact fp32 raw recompute (whole token)
    if (__any(fabsf(raw - (rmax - 1.5f)) < MRG_RAW)) {
        float s0 = 0.f, s1 = 0.f, s2 = 0.f, s3 = 0.f;
        const float4* xr = reinterpret_cast<const float4*>(x + (size_t)t * DDIM);
        const float4* wr = reinterpret_cast<const float4*>(gateW + (size_t)e * DDIM);
        for (int k = 0; k < DDIM / 4; ++k) {
            const float4 a = xr[k], b = wr[k];
            s0 = fmaf(a.x, b.x, s0); s1 = fmaf(a.y, b.y, s1);
            s2 = fmaf(a.z, b.z, s2); s3 = fmaf(a.w, b.w, s3);
        }
        raw = (s0 + s1) + (s2 + s3);
        rmax = raw;
        #pragma unroll
        for (int off = 32; off; off >>= 1) rmax = fmaxf(rmax, __shfl_xor(rmax, off));
    }

    const bool safe = (raw >= rmax - 1.5f);
    float m = safe ? wm : NEG_INF;

    // top-3 (value desc, lowest index on ties = jax.lax.top_k)
    float v1 = m; int e1 = e;
    #pragma unroll
    for (int off = 32; off; off >>= 1) {
        const float ov = __shfl_xor(v1, off); const int oi = __shfl_xor(e1, off);
        if (ov > v1 || (ov == v1 && oi < e1)) { v1 = ov; e1 = oi; }
    }
    float v2 = (e == e1) ? -3.0e38f : m; int e2 = e;
    #pragma unroll
    for (int off = 32; off; off >>= 1) {
        const float ov = __shfl_xor(v2, off); const int oi = __shfl_xor(e2, off);
        if (ov > v2 || (ov == v2 && oi < e2)) { v2 = ov; e2 = oi; }
    }
    float v3 = (e == e1 || e == e2) ? -3.0e38f : m; int e3 = e;
    #pragma unroll
    for (int off = 32; off; off >>= 1) {
        const float ov = __shfl_xor(v3, off); const int oi = __shfl_xor(e3, off);
        if (ov > v3 || (ov == v3 && oi < e3)) { v3 = ov; e3 = oi; }
    }

    // guard 2: close wm ordering among safe candidates -> exact fp32 wm recompute
    const bool wmRisk = (v2 > NEG_INF + 1.0f && v1 - v2 < MRG_WM) ||
                        (v3 > NEG_INF + 1.0f && v2 - v3 < MRG_WM);
    if (__any(wmRisk)) {
        float s0 = 0.f, s1 = 0.f, s2 = 0.f, s3 = 0.f;
        const float* xr = x + (size_t)t * DDIM;
        for (int k = 0; k < DDIM; k += 4) {
            s0 = fmaf(xr[k + 0], secret[(size_t)(k + 0) * NEXP + e], s0);
            s1 = fmaf(xr[k + 1], secret[(size_t)(k + 1) * NEXP + e], s1);
            s2 = fmaf(xr[k + 2], secret[(size_t)(k + 2) * NEXP + e], s2);
            s3 = fmaf(xr[k + 3], secret[(size_t)(k + 3) * NEXP + e], s3);
        }
        m = safe ? ((s0 + s1) + (s2 + s3)) : NEG_INF;
        v1 = m; e1 = e;
        #pragma unroll
        for (int off = 32; off; off >>= 1) {
            const float ov = __shfl_xor(v1, off); const int oi = __shfl_xor(e1, off);
            if (ov > v1 || (ov == v1 && oi < e1)) { v1 = ov; e1 = oi; }
        }
        v2 = (e == e1) ? -3.0e38f : m; e2 = e;
        #pragma unroll
        for (int off = 32; off; off >>= 1) {
            const float ov = __shfl_xor(v2, off); const int oi = __shfl_xor(e2, off);
            if (ov > v2 || (ov == v2 && oi < e2)) { v2 = ov; e2 = oi; }
        }
    }

    const float l1 = __shfl(raw, e1);
    const float l2 = __shfl(raw, e2);

    if (e == 0) {
        const float mm = fmaxf(l1, l2);
        const float x1 = expf(l1 - mm), x2 = expf(l2 - mm);
        const float inv = 1.0f / (x1 + x2);
        out[(size_t)t * 2 + 0] = x1 * inv;
        out[(size_t)t * 2 + 1] = x2 * inv;
        out[(size_t)2 * ntok + t * 2 + 0] = (float)e1;
        out[(size_t)2 * ntok + t * 2 + 1] = (float)e2;
    }
}

extern "C" void kernel_launch(void* const* d_in, const int* in_sizes, int n_in,
                              void* d_out, int out_size, void* d_ws, size_t ws_size,
                              hipStream_t stream) {
    const float* x      = (const float*)d_in[0];
    const float* gateW  = (const float*)d_in[1];
    const float* secret = (const float*)d_in[2];
    float* out = (float*)d_out;

    const int ntok = in_sizes[0] / DDIM;                 // 16384
    uint4* wsB = (uint4*)d_ws;                           // 1 MB fragments
    float* wsP = (float*)((char*)d_ws + (2u << 20));     // partials [4][ntok][128]

    prep_b<<<64, 512, 0, stream>>>(gateW, secret, wsB);
    gemm_p<<<(ntok / TOKB) * KSPL, 512, 0, stream>>>(x, (const char*)wsB, wsP, ntok);
    router_k<KSPL><<<ntok / 4, 256, 0, stream>>>(wsP, x, gateW, secret, out, ntok);
}